// Round 3
// baseline (1737.541 us; speedup 1.0000x reference)
//
#include <hip/hip_runtime.h>
#include <math.h>

#define DIMN   200
#define NNODES 100000
#define NREL   500
#define NEDGES 200000
#define KSTEPS 7            // K padded 200 -> 224 = 7*32
#define NB16   16           // N padded 200 -> 256
#define WPK_ELEMS (KSTEPS * NB16 * 64 * 8)   // 57344 bf16 per weight
#define SCAN_B 1024
#define NBN    6256         // node fragment blocks (16 rows each), covers 128-row grid (782*8)
#define FRAG_STRIDE 3584    // elems per frag block = KSTEPS*512

typedef float  v4f  __attribute__((ext_vector_type(4)));
typedef __bf16 v8bf __attribute__((ext_vector_type(8)));

// A-fragment layout: element (row r in block nb, k = c*8+j) at
//   (nb*KSTEPS + c/4)*512 + (c%4)*128 + r*8 + j        (c = chunk 0..27)
__device__ __forceinline__ size_t frag_chunk(int nb, int c, int r) {
    return (size_t)(nb * KSTEPS + (c >> 2)) * 512 + (size_t)((c & 3) * 128 + r * 8);
}

// ---------------- prologue l2norm: fp32 rows -> bf16 row + optional bf16 frag ----------------
__launch_bounds__(256)
__global__ void l2norm_pro(const float* __restrict__ in, __bf16* __restrict__ outR,
                           __bf16* __restrict__ outF, int nrows)
{
    int idx  = blockIdx.x * 256 + threadIdx.x;
    int node = idx >> 5;
    int ch   = idx & 31;
    if (node >= nrows) return;
    float v[8] = {};
    if (ch < 25) {
        const float4* p = (const float4*)(in + (size_t)node * DIMN + ch * 8);
        float4 f0 = p[0], f1 = p[1];
        v[0]=f0.x; v[1]=f0.y; v[2]=f0.z; v[3]=f0.w;
        v[4]=f1.x; v[5]=f1.y; v[6]=f1.z; v[7]=f1.w;
    }
    float ss = 0.0f;
    #pragma unroll
    for (int k = 0; k < 8; ++k) ss += v[k] * v[k];
    #pragma unroll
    for (int off = 16; off; off >>= 1) ss += __shfl_xor(ss, off, 64);
    float s = 1.0f / fmaxf(sqrtf(ss), 1e-12f);
    #pragma unroll
    for (int k = 0; k < 8; ++k) v[k] *= s;
    if (ch < 25) {
        v8bf o;
        #pragma unroll
        for (int k = 0; k < 8; ++k) o[k] = (__bf16)v[k];
        *(v8bf*)(outR + (size_t)node * DIMN + ch * 8) = o;
    }
    if (outF && ch < 28) {
        v8bf o;
        #pragma unroll
        for (int k = 0; k < 8; ++k) o[k] = (ch < 25) ? (__bf16)v[k] : (__bf16)0.0f;
        *(v8bf*)(outF + frag_chunk(node >> 4, ch, node & 15)) = o;
    }
}

// ---------------- CSR build ----------------
__launch_bounds__(256)
__global__ void edge_hist(const int* __restrict__ edges, int* __restrict__ counts, int nedges)
{
    int e = blockIdx.x * 256 + threadIdx.x;
    if (e < nedges) atomicAdd(&counts[edges[e * 3 + 2]], 1);
}

__launch_bounds__(SCAN_B)
__global__ void scan1(const int* __restrict__ counts, int* __restrict__ tmp,
                      int* __restrict__ bsum, int n)
{
    __shared__ int sh[SCAN_B];
    int i = blockIdx.x * SCAN_B + threadIdx.x;
    int v = (i < n) ? counts[i] : 0;
    sh[threadIdx.x] = v;
    __syncthreads();
    for (int off = 1; off < SCAN_B; off <<= 1) {
        int t = (threadIdx.x >= off) ? sh[threadIdx.x - off] : 0;
        __syncthreads();
        sh[threadIdx.x] += t;
        __syncthreads();
    }
    if (i < n) tmp[i] = sh[threadIdx.x];
    if (threadIdx.x == SCAN_B - 1) bsum[blockIdx.x] = sh[threadIdx.x];
}

__launch_bounds__(128)
__global__ void scan2(int* __restrict__ bsum, int nb)
{
    __shared__ int sh[128];
    int v = (threadIdx.x < nb) ? bsum[threadIdx.x] : 0;
    sh[threadIdx.x] = v;
    __syncthreads();
    for (int off = 1; off < 128; off <<= 1) {
        int t = (threadIdx.x >= off) ? sh[threadIdx.x - off] : 0;
        __syncthreads();
        sh[threadIdx.x] += t;
        __syncthreads();
    }
    if (threadIdx.x < nb) bsum[threadIdx.x] = sh[threadIdx.x] - v;
}

__launch_bounds__(SCAN_B)
__global__ void scan3(const int* __restrict__ tmp, const int* __restrict__ bsum,
                      int* __restrict__ offs, int n)
{
    int i = blockIdx.x * SCAN_B + threadIdx.x;
    if (i < n) offs[i + 1] = tmp[i] + bsum[blockIdx.x];
    if (i == 0) offs[0] = 0;
}

__launch_bounds__(256)
__global__ void edge_fill(const int* __restrict__ edges, const int* __restrict__ offs,
                          int* __restrict__ cursor, int2* __restrict__ sorted, int nedges)
{
    int e = blockIdx.x * 256 + threadIdx.x;
    if (e >= nedges) return;
    int s = edges[e * 3 + 0];
    int r = edges[e * 3 + 1];
    int d = edges[e * 3 + 2];
    int p = offs[d] + atomicAdd(&cursor[d], 1);
    sorted[p] = make_int2(s, r);
}

// ---------------- aggregate in h-space: S = segsum(x[src] + r[rel]) / max(deg,1) ----------------
// one wave per node; lanes 0..24 gather x chunks, lanes 32..56 gather r chunks; write S in frag layout
__launch_bounds__(256)
__global__ void agg_S(const int* __restrict__ offs, const int2* __restrict__ sorted,
                      const __bf16* __restrict__ XR, const __bf16* __restrict__ RnR,
                      __bf16* __restrict__ SF, int nnodes)
{
    int wave = (int)((blockIdx.x * blockDim.x + threadIdx.x) >> 6);
    int lane = threadIdx.x & 63;
    if (wave >= nnodes) return;
    int beg = offs[wave], end = offs[wave + 1];
    int ch = lane & 31;
    bool act = ch < 25;

    float acc[8] = {};
    for (int e = beg; e < end; ++e) {
        int2 sr = sorted[e];
        const __bf16* base = (lane < 32) ? (XR + (size_t)sr.x * DIMN)
                                         : (RnR + (size_t)sr.y * DIMN);
        v8bf v = {};
        if (act) v = *(const v8bf*)(base + ch * 8);
        #pragma unroll
        for (int k = 0; k < 8; ++k) acc[k] += (float)v[k];
    }
    #pragma unroll
    for (int k = 0; k < 8; ++k) acc[k] += __shfl_xor(acc[k], 32, 64);

    float rdeg = 1.0f / fmaxf((float)(end - beg), 1.0f);
    if (lane < 32 && ch < 28) {
        v8bf o;
        #pragma unroll
        for (int k = 0; k < 8; ++k) o[k] = act ? (__bf16)(acc[k] * rdeg) : (__bf16)0.0f;
        *(v8bf*)(SF + frag_chunk(wave >> 4, ch, wave & 15)) = o;
    }
}

// ---------------- weight pack: fp32 W[200x200] -> bf16 MFMA-B-fragment-linear ----------------
__launch_bounds__(256)
__global__ void pack_w(const float* __restrict__ W0, const float* __restrict__ W1,
                       const float* __restrict__ W2, const float* __restrict__ W3,
                       const float* __restrict__ W4, __bf16* __restrict__ out)
{
    int id = blockIdx.x * 256 + threadIdx.x;
    const int nchunk = KSTEPS * NB16 * 64;        // 7168
    if (id >= 5 * nchunk) return;
    int wi = id / nchunk;
    int c  = id % nchunk;
    const float* W = wi == 0 ? W0 : wi == 1 ? W1 : wi == 2 ? W2 : wi == 3 ? W3 : W4;
    int s    = c >> 10;
    int nb   = (c & 1023) >> 6;
    int lane = c & 63;
    int kbase = s * 32 + (lane >> 4) * 8;
    int n     = nb * 16 + (lane & 15);
    __bf16* dst = out + (size_t)wi * WPK_ELEMS + (size_t)c * 8;
    #pragma unroll
    for (int j = 0; j < 8; ++j) {
        int k = kbase + j;
        float v = (k < DIMN && n < DIMN) ? W[k * DIMN + n] : 0.0f;
        dst[j] = (__bf16)v;
    }
}

// ---------------- G1: Out = A1@W1 + A2@W2 ; BM=128 (was 64) ----------------
// Rationale (R2): per-block weight L2 traffic is fixed (229KB); doubling BM halves
// the per-output weight traffic. Epilogue emits in two 64-row halves reusing one
// T[64][264] so LDS stays 33.8KB.
__launch_bounds__(256)
__global__ void gemm_dual(const __bf16* __restrict__ A1, const __bf16* __restrict__ W1,
                          const __bf16* __restrict__ A2, const __bf16* __restrict__ W2,
                          __bf16* __restrict__ OutR, __bf16* __restrict__ OutF, int M)
{
    const int tid  = threadIdx.x;
    const int w    = tid >> 6;
    const int lane = tid & 63;
    const int rlo  = lane & 15;
    const int g    = lane >> 4;
    const int nb0  = blockIdx.x * 8;
    const int bm   = blockIdx.x * 128;

    __shared__ __bf16 T[64][264];

    v4f acc[8][4];
    #pragma unroll
    for (int mi = 0; mi < 8; ++mi)
        #pragma unroll
        for (int ni = 0; ni < 4; ++ni)
            acc[mi][ni] = (v4f){0.f, 0.f, 0.f, 0.f};

    const __bf16* w1b = W1 + (size_t)(w * 4 * 64 + lane) * 8;
    const __bf16* w2b = W2 + (size_t)(w * 4 * 64 + lane) * 8;

    for (int s = 0; s < KSTEPS; ++s) {
        v8bf b1[4], b2[4];
        #pragma unroll
        for (int ni = 0; ni < 4; ++ni) {
            b1[ni] = *(const v8bf*)(w1b + ((size_t)s * NB16 * 64 + ni * 64) * 8);
            b2[ni] = *(const v8bf*)(w2b + ((size_t)s * NB16 * 64 + ni * 64) * 8);
        }
        #pragma unroll
        for (int mi = 0; mi < 8; ++mi) {
            size_t aoff = (size_t)((nb0 + mi) * KSTEPS + s) * 512 + lane * 8;
            v8bf a1 = *(const v8bf*)(A1 + aoff);
            v8bf a2 = *(const v8bf*)(A2 + aoff);
            #pragma unroll
            for (int ni = 0; ni < 4; ++ni)
                acc[mi][ni] = __builtin_amdgcn_mfma_f32_16x16x32_bf16(a1, b1[ni], acc[mi][ni], 0, 0, 0);
            #pragma unroll
            for (int ni = 0; ni < 4; ++ni)
                acc[mi][ni] = __builtin_amdgcn_mfma_f32_16x16x32_bf16(a2, b2[ni], acc[mi][ni], 0, 0, 0);
        }
    }

    // two 64-row halves through the same T buffer
    #pragma unroll
    for (int h2 = 0; h2 < 2; ++h2) {
        if (h2) __syncthreads();   // previous half's emits done before overwrite
        #pragma unroll
        for (int mi = 0; mi < 4; ++mi)
            #pragma unroll
            for (int reg = 0; reg < 4; ++reg)
                #pragma unroll
                for (int ni = 0; ni < 4; ++ni)
                    T[mi * 16 + g * 4 + reg][w * 64 + ni * 16 + rlo] = (__bf16)acc[h2 * 4 + mi][ni][reg];
        __syncthreads();

        // frag emit: 4 nb * 7 s * 64 slots = 1792
        #pragma unroll
        for (int j = 0; j < 7; ++j) {
            int it = tid + j * 256;
            int slot = it & 63;
            int q = it >> 6;          // 0..27
            int s = q % 7, nb = q / 7;
            *(v8bf*)(OutF + (size_t)((nb0 + h2 * 4 + nb) * KSTEPS + s) * 512 + slot * 8) =
                *(const v8bf*)&T[nb * 16 + (slot & 15)][s * 32 + (slot >> 4) * 8];
        }
        // row emit: 64 rows * 25 chunks = 1600
        #pragma unroll
        for (int j = 0; j < 7; ++j) {
            int it = tid + j * 256;
            if (it < 1600) {
                int row = it / 25, ch = it - row * 25;
                int gr = bm + h2 * 64 + row;
                if (gr < M)
                    *(v8bf*)(OutR + (size_t)gr * DIMN + ch * 8) = *(const v8bf*)&T[row][ch * 8];
            }
        }
    }
}

// ---------------- G2 mega: cur = l2norm(A1@W1 + A2@W2); gate = sigmoid(A3@W3 + bias);
//                  h' = l2norm(gate*cur + (1-gate)*h)
// BM=64 (was 32, R2): halves per-output weight L2 traffic (344KB/block fixed cost).
// acc 32 v4f (AGPR) + ~85 arch VGPR -> 2 waves/SIMD; LDS ~35.8KB not limiting.
__launch_bounds__(256)
__global__ void gemm_mega(const __bf16* __restrict__ A1, const __bf16* __restrict__ W1,
                          const __bf16* __restrict__ A2, const __bf16* __restrict__ W2,
                          const __bf16* __restrict__ A3, const __bf16* __restrict__ W3,
                          const float* __restrict__ Bias,
                          __bf16* __restrict__ HR, __bf16* __restrict__ HF,
                          float* __restrict__ DoutF, int M, int finalStep)
{
    const int tid  = threadIdx.x;
    const int w    = tid >> 6;
    const int lane = tid & 63;
    const int rlo  = lane & 15;
    const int g    = lane >> 4;
    const int nb0  = blockIdx.x * 4;
    const int bm   = blockIdx.x * 64;

    __shared__ __bf16 T[64][264];
    __shared__ float  rsq1[64][4];
    __shared__ float  rsq2[64][4];

    v4f acc1[4][4], acc2[4][4];
    #pragma unroll
    for (int mi = 0; mi < 4; ++mi)
        #pragma unroll
        for (int ni = 0; ni < 4; ++ni) {
            acc1[mi][ni] = (v4f){0.f, 0.f, 0.f, 0.f};
            acc2[mi][ni] = (v4f){0.f, 0.f, 0.f, 0.f};
        }

    const __bf16* w1b = W1 + (size_t)(w * 4 * 64 + lane) * 8;
    const __bf16* w2b = W2 + (size_t)(w * 4 * 64 + lane) * 8;
    const __bf16* w3b = W3 + (size_t)(w * 4 * 64 + lane) * 8;

    for (int s = 0; s < KSTEPS; ++s) {
        v8bf b1[4], b2[4], b3[4];
        #pragma unroll
        for (int ni = 0; ni < 4; ++ni) {
            size_t bo = ((size_t)s * NB16 * 64 + ni * 64) * 8;
            b1[ni] = *(const v8bf*)(w1b + bo);
            b2[ni] = *(const v8bf*)(w2b + bo);
            b3[ni] = *(const v8bf*)(w3b + bo);
        }
        #pragma unroll
        for (int mi = 0; mi < 4; ++mi) {
            size_t aoff = (size_t)((nb0 + mi) * KSTEPS + s) * 512 + lane * 8;
            v8bf a1 = *(const v8bf*)(A1 + aoff);
            v8bf a2 = *(const v8bf*)(A2 + aoff);
            v8bf a3 = *(const v8bf*)(A3 + aoff);
            #pragma unroll
            for (int ni = 0; ni < 4; ++ni)
                acc1[mi][ni] = __builtin_amdgcn_mfma_f32_16x16x32_bf16(a1, b1[ni], acc1[mi][ni], 0, 0, 0);
            #pragma unroll
            for (int ni = 0; ni < 4; ++ni)
                acc1[mi][ni] = __builtin_amdgcn_mfma_f32_16x16x32_bf16(a2, b2[ni], acc1[mi][ni], 0, 0, 0);
            #pragma unroll
            for (int ni = 0; ni < 4; ++ni)
                acc2[mi][ni] = __builtin_amdgcn_mfma_f32_16x16x32_bf16(a3, b3[ni], acc2[mi][ni], 0, 0, 0);
        }
    }

    // cur row sums-of-squares
    #pragma unroll
    for (int mi = 0; mi < 4; ++mi)
        #pragma unroll
        for (int reg = 0; reg < 4; ++reg) {
            float ss = 0.0f;
            #pragma unroll
            for (int ni = 0; ni < 4; ++ni) ss += acc1[mi][ni][reg] * acc1[mi][ni][reg];
            ss += __shfl_xor(ss, 1, 64);
            ss += __shfl_xor(ss, 2, 64);
            ss += __shfl_xor(ss, 4, 64);
            ss += __shfl_xor(ss, 8, 64);
            if (rlo == 0) rsq1[mi * 16 + g * 4 + reg][w] = ss;
        }
    // stage h rows into T (buffer reused; output written only after blend completes)
    #pragma unroll
    for (int j = 0; j < 7; ++j) {
        int it = tid + j * 256;
        if (it < 1600) {
            int row = it / 25, ch = it - row * 25;
            int gr = bm + row;
            v8bf hv = {};
            if (gr < M) hv = *(const v8bf*)(HR + (size_t)gr * DIMN + ch * 8);
            *(v8bf*)&T[row][ch * 8] = hv;
        }
    }
    __syncthreads();

    // blend: v = gate*cur + (1-gate)*h  (store into acc1), second row reduce
    #pragma unroll
    for (int mi = 0; mi < 4; ++mi)
        #pragma unroll
        for (int reg = 0; reg < 4; ++reg) {
            int rl = mi * 16 + g * 4 + reg;
            float tot = rsq1[rl][0] + rsq1[rl][1] + rsq1[rl][2] + rsq1[rl][3];
            float sc1 = 1.0f / fmaxf(sqrtf(tot), 1e-12f);
            float ss = 0.0f;
            #pragma unroll
            for (int ni = 0; ni < 4; ++ni) {
                int c = w * 64 + ni * 16 + rlo;
                float v = 0.0f;
                if (c < DIMN) {
                    float cur = acc1[mi][ni][reg] * sc1;
                    float gg  = 1.0f / (1.0f + __expf(-(acc2[mi][ni][reg] + Bias[c])));
                    float hh  = (float)T[rl][c];
                    v = gg * cur + (1.0f - gg) * hh;
                }
                acc1[mi][ni][reg] = v;
                ss += v * v;
            }
            ss += __shfl_xor(ss, 1, 64);
            ss += __shfl_xor(ss, 2, 64);
            ss += __shfl_xor(ss, 4, 64);
            ss += __shfl_xor(ss, 8, 64);
            if (rlo == 0) rsq2[rl][w] = ss;
        }
    __syncthreads();

    // final scale -> T (overwrites staged h; all h reads completed before the barrier above)
    #pragma unroll
    for (int mi = 0; mi < 4; ++mi)
        #pragma unroll
        for (int reg = 0; reg < 4; ++reg) {
            int rl = mi * 16 + g * 4 + reg;
            float tot = rsq2[rl][0] + rsq2[rl][1] + rsq2[rl][2] + rsq2[rl][3];
            float sc2 = 1.0f / fmaxf(sqrtf(tot), 1e-12f);
            #pragma unroll
            for (int ni = 0; ni < 4; ++ni) {
                int c = w * 64 + ni * 16 + rlo;
                T[rl][c] = (__bf16)(acc1[mi][ni][reg] * sc2);
            }
        }
    __syncthreads();

    if (!finalStep) {
        // h' rows: 64 rows * 25 chunks = 1600
        #pragma unroll
        for (int j = 0; j < 7; ++j) {
            int it = tid + j * 256;
            if (it < 1600) {
                int row = it / 25, ch = it - row * 25;
                int gr = bm + row;
                if (gr < M)
                    *(v8bf*)(HR + (size_t)gr * DIMN + ch * 8) = *(const v8bf*)&T[row][ch * 8];
            }
        }
        // h' frag: 4 nb * 7 s * 64 slots = 1792
        #pragma unroll
        for (int j = 0; j < 7; ++j) {
            int it = tid + j * 256;
            int slot = it & 63;
            int q = it >> 6;          // 0..27
            int s = q % 7, nb = q / 7;
            *(v8bf*)(HF + (size_t)((nb0 + nb) * KSTEPS + s) * 512 + slot * 8) =
                *(const v8bf*)&T[nb * 16 + (slot & 15)][s * 32 + (slot >> 4) * 8];
        }
    } else {
        // fp32 output rows
        #pragma unroll
        for (int j = 0; j < 7; ++j) {
            int it = tid + j * 256;
            if (it < 1600) {
                int row = it / 25, ch = it - row * 25;
                int gr = bm + row;
                if (gr < M) {
                    v8bf o = *(const v8bf*)&T[row][ch * 8];
                    float4* q0 = (float4*)(DoutF + (size_t)gr * DIMN + ch * 8);
                    q0[0] = make_float4((float)o[0], (float)o[1], (float)o[2], (float)o[3]);
                    q0[1] = make_float4((float)o[4], (float)o[5], (float)o[6], (float)o[7]);
                }
            }
        }
    }
}

extern "C" void kernel_launch(void* const* d_in, const int* in_sizes, int n_in,
                              void* d_out, int out_size, void* d_ws, size_t ws_size,
                              hipStream_t stream)
{
    const int*   edges = (const int*)  d_in[0];
    const float* ent   = (const float*)d_in[1];
    const float* relE  = (const float*)d_in[2];
    const float* Wm1   = (const float*)d_in[3];
    const float* Wl1   = (const float*)d_in[4];
    const float* Wm2   = (const float*)d_in[5];
    const float* Wl2   = (const float*)d_in[6];
    const float* Wtg   = (const float*)d_in[7];
    const float* bias  = (const float*)d_in[8];
    float* Dout = (float*)d_out;

    const size_t NM    = (size_t)NNODES * DIMN;
    const size_t FRAGN = (size_t)NBN * FRAG_STRIDE;

    __bf16* hR   = (__bf16*)d_ws;                      // h row-major (gather + mega-epilogue)
    __bf16* hF   = hR + NM;                            // h fragment (GEMM-A)
    __bf16* SF   = hF + FRAGN;                         // S1/S2 fragment
    __bf16* BR   = SF + FRAGN;                         // layer-1 out rows (gather)
    __bf16* BF   = BR + NM;                            // layer-1 out fragment
    __bf16* RnR  = BF + FRAGN;                         // normalized relations rows
    __bf16* Wpk  = RnR + (size_t)NREL * DIMN;          // 5 packed weights
    __bf16* pWm1 = Wpk + 0 * (size_t)WPK_ELEMS;
    __bf16* pWl1 = Wpk + 1 * (size_t)WPK_ELEMS;
    __bf16* pWm2 = Wpk + 2 * (size_t)WPK_ELEMS;
    __bf16* pWl2 = Wpk + 3 * (size_t)WPK_ELEMS;
    __bf16* pWtg = Wpk + 4 * (size_t)WPK_ELEMS;
    int*  counts = (int*)(Wpk + 5 * (size_t)WPK_ELEMS);
    int2* sorted = (int2*)(counts + NNODES);
    int*  offs   = (int*)(sorted + NEDGES);
    int*  bsum   = offs + (NNODES + 1);
    int*  stmp   = bsum + 256;

    dim3 blk(256);
    const int GD = (NNODES + 127) / 128;    // 782  (dual, BM=128)
    const int GM = (NNODES + 63) / 64;      // 1563 (mega, BM=64)
    dim3 ngrid32((NNODES * 32 + 255) / 256);
    dim3 rgrid32((NREL * 32 + 255) / 256);
    dim3 agrid((NNODES + 3) / 4);
    dim3 egrid((NEDGES + 255) / 256);
    const int NSB = (NNODES + SCAN_B - 1) / SCAN_B;

    pack_w<<<dim3((5 * KSTEPS * NB16 * 64 + 255) / 256), blk, 0, stream>>>(Wm1, Wl1, Wm2, Wl2, Wtg, Wpk);
    l2norm_pro<<<ngrid32, blk, 0, stream>>>(ent, hR, hF, NNODES);
    l2norm_pro<<<rgrid32, blk, 0, stream>>>(relE, RnR, nullptr, NREL);

    for (int t = 0; t < 3; ++t) {
        const int* ed = edges + (size_t)t * NEDGES * 3;
        // ---- CSR build ----
        hipMemsetAsync(counts, 0, NNODES * sizeof(int), stream);
        edge_hist<<<egrid, blk, 0, stream>>>(ed, counts, NEDGES);
        scan1<<<NSB, SCAN_B, 0, stream>>>(counts, stmp, bsum, NNODES);
        scan2<<<1, 128, 0, stream>>>(bsum, NSB);
        scan3<<<NSB, SCAN_B, 0, stream>>>(stmp, bsum, offs, NNODES);
        hipMemsetAsync(counts, 0, NNODES * sizeof(int), stream);   // cursor
        edge_fill<<<egrid, blk, 0, stream>>>(ed, offs, counts, sorted, NEDGES);
        // ---- layer 1 (linearity: aggregate in h-space, then fused dual-stream GEMM) ----
        agg_S<<<agrid, blk, 0, stream>>>(offs, sorted, hR, RnR, SF, NNODES);
        gemm_dual<<<GD, blk, 0, stream>>>(SF, pWm1, hF, pWl1, BR, BF, NNODES);
        // ---- layer 2 + gate + blend + norms (mega) ----
        agg_S<<<agrid, blk, 0, stream>>>(offs, sorted, BR, RnR, SF, NNODES);
        gemm_mega<<<GM, blk, 0, stream>>>(SF, pWm2, BF, pWl2, hF, pWtg, bias,
                                          hR, hF, Dout, NNODES, (t == 2) ? 1 : 0);
    }
}

// Round 4
// 1039.297 us; speedup vs baseline: 1.6718x; 1.6718x over previous
//
#include <hip/hip_runtime.h>
#include <math.h>

#define DIMN   200
#define NNODES 100000
#define NREL   500
#define NEDGES 200000
#define KSTEPS 7            // K padded 200 -> 224 = 7*32
#define NB16   16           // N padded 200 -> 256
#define WPK_ELEMS (KSTEPS * NB16 * 64 * 8)   // 57344 bf16 per weight
#define SCAN_B 1024
#define NBN    6252         // node fragment blocks (16 rows each), covers 64-row grid
#define FRAG_STRIDE 3584    // elems per frag block = KSTEPS*512

typedef float  v4f  __attribute__((ext_vector_type(4)));
typedef __bf16 v8bf __attribute__((ext_vector_type(8)));

// A-fragment layout: element (row r in block nb, k = c*8+j) at
//   (nb*KSTEPS + c/4)*512 + (c%4)*128 + r*8 + j        (c = chunk 0..27)
__device__ __forceinline__ size_t frag_chunk(int nb, int c, int r) {
    return (size_t)(nb * KSTEPS + (c >> 2)) * 512 + (size_t)((c & 3) * 128 + r * 8);
}

// ---------------- prologue l2norm: fp32 rows -> bf16 row + optional bf16 frag ----------------
__launch_bounds__(256)
__global__ void l2norm_pro(const float* __restrict__ in, __bf16* __restrict__ outR,
                           __bf16* __restrict__ outF, int nrows)
{
    int idx  = blockIdx.x * 256 + threadIdx.x;
    int node = idx >> 5;
    int ch   = idx & 31;
    if (node >= nrows) return;
    float v[8] = {};
    if (ch < 25) {
        const float4* p = (const float4*)(in + (size_t)node * DIMN + ch * 8);
        float4 f0 = p[0], f1 = p[1];
        v[0]=f0.x; v[1]=f0.y; v[2]=f0.z; v[3]=f0.w;
        v[4]=f1.x; v[5]=f1.y; v[6]=f1.z; v[7]=f1.w;
    }
    float ss = 0.0f;
    #pragma unroll
    for (int k = 0; k < 8; ++k) ss += v[k] * v[k];
    #pragma unroll
    for (int off = 16; off; off >>= 1) ss += __shfl_xor(ss, off, 64);
    float s = 1.0f / fmaxf(sqrtf(ss), 1e-12f);
    #pragma unroll
    for (int k = 0; k < 8; ++k) v[k] *= s;
    if (ch < 25) {
        v8bf o;
        #pragma unroll
        for (int k = 0; k < 8; ++k) o[k] = (__bf16)v[k];
        *(v8bf*)(outR + (size_t)node * DIMN + ch * 8) = o;
    }
    if (outF && ch < 28) {
        v8bf o;
        #pragma unroll
        for (int k = 0; k < 8; ++k) o[k] = (ch < 25) ? (__bf16)v[k] : (__bf16)0.0f;
        *(v8bf*)(outF + frag_chunk(node >> 4, ch, node & 15)) = o;
    }
}

// ---------------- CSR build ----------------
__launch_bounds__(256)
__global__ void edge_hist(const int* __restrict__ edges, int* __restrict__ counts, int nedges)
{
    int e = blockIdx.x * 256 + threadIdx.x;
    if (e < nedges) atomicAdd(&counts[edges[e * 3 + 2]], 1);
}

__launch_bounds__(SCAN_B)
__global__ void scan1(const int* __restrict__ counts, int* __restrict__ tmp,
                      int* __restrict__ bsum, int n)
{
    __shared__ int sh[SCAN_B];
    int i = blockIdx.x * SCAN_B + threadIdx.x;
    int v = (i < n) ? counts[i] : 0;
    sh[threadIdx.x] = v;
    __syncthreads();
    for (int off = 1; off < SCAN_B; off <<= 1) {
        int t = (threadIdx.x >= off) ? sh[threadIdx.x - off] : 0;
        __syncthreads();
        sh[threadIdx.x] += t;
        __syncthreads();
    }
    if (i < n) tmp[i] = sh[threadIdx.x];
    if (threadIdx.x == SCAN_B - 1) bsum[blockIdx.x] = sh[threadIdx.x];
}

__launch_bounds__(128)
__global__ void scan2(int* __restrict__ bsum, int nb)
{
    __shared__ int sh[128];
    int v = (threadIdx.x < nb) ? bsum[threadIdx.x] : 0;
    sh[threadIdx.x] = v;
    __syncthreads();
    for (int off = 1; off < 128; off <<= 1) {
        int t = (threadIdx.x >= off) ? sh[threadIdx.x - off] : 0;
        __syncthreads();
        sh[threadIdx.x] += t;
        __syncthreads();
    }
    if (threadIdx.x < nb) bsum[threadIdx.x] = sh[threadIdx.x] - v;
}

__launch_bounds__(SCAN_B)
__global__ void scan3(const int* __restrict__ tmp, const int* __restrict__ bsum,
                      int* __restrict__ offs, int n)
{
    int i = blockIdx.x * SCAN_B + threadIdx.x;
    if (i < n) offs[i + 1] = tmp[i] + bsum[blockIdx.x];
    if (i == 0) offs[0] = 0;
}

__launch_bounds__(256)
__global__ void edge_fill(const int* __restrict__ edges, const int* __restrict__ offs,
                          int* __restrict__ cursor, int2* __restrict__ sorted, int nedges)
{
    int e = blockIdx.x * 256 + threadIdx.x;
    if (e >= nedges) return;
    int s = edges[e * 3 + 0];
    int r = edges[e * 3 + 1];
    int d = edges[e * 3 + 2];
    int p = offs[d] + atomicAdd(&cursor[d], 1);
    sorted[p] = make_int2(s, r);
}

// ---------------- aggregate in h-space: S = segsum(x[src] + r[rel]) / max(deg,1) ----------------
// one wave per node; lanes 0..24 gather x chunks, lanes 32..56 gather r chunks; write S in frag layout
__launch_bounds__(256)
__global__ void agg_S(const int* __restrict__ offs, const int2* __restrict__ sorted,
                      const __bf16* __restrict__ XR, const __bf16* __restrict__ RnR,
                      __bf16* __restrict__ SF, int nnodes)
{
    int wave = (int)((blockIdx.x * blockDim.x + threadIdx.x) >> 6);
    int lane = threadIdx.x & 63;
    if (wave >= nnodes) return;
    int beg = offs[wave], end = offs[wave + 1];
    int ch = lane & 31;
    bool act = ch < 25;

    float acc[8] = {};
    for (int e = beg; e < end; ++e) {
        int2 sr = sorted[e];
        const __bf16* base = (lane < 32) ? (XR + (size_t)sr.x * DIMN)
                                         : (RnR + (size_t)sr.y * DIMN);
        v8bf v = {};
        if (act) v = *(const v8bf*)(base + ch * 8);
        #pragma unroll
        for (int k = 0; k < 8; ++k) acc[k] += (float)v[k];
    }
    #pragma unroll
    for (int k = 0; k < 8; ++k) acc[k] += __shfl_xor(acc[k], 32, 64);

    float rdeg = 1.0f / fmaxf((float)(end - beg), 1.0f);
    if (lane < 32 && ch < 28) {
        v8bf o;
        #pragma unroll
        for (int k = 0; k < 8; ++k) o[k] = act ? (__bf16)(acc[k] * rdeg) : (__bf16)0.0f;
        *(v8bf*)(SF + frag_chunk(wave >> 4, ch, wave & 15)) = o;
    }
}

// ---------------- weight pack: fp32 W[200x200] -> bf16 MFMA-B-fragment-linear ----------------
__launch_bounds__(256)
__global__ void pack_w(const float* __restrict__ W0, const float* __restrict__ W1,
                       const float* __restrict__ W2, const float* __restrict__ W3,
                       const float* __restrict__ W4, __bf16* __restrict__ out)
{
    int id = blockIdx.x * 256 + threadIdx.x;
    const int nchunk = KSTEPS * NB16 * 64;        // 7168
    if (id >= 5 * nchunk) return;
    int wi = id / nchunk;
    int c  = id % nchunk;
    const float* W = wi == 0 ? W0 : wi == 1 ? W1 : wi == 2 ? W2 : wi == 3 ? W3 : W4;
    int s    = c >> 10;
    int nb   = (c & 1023) >> 6;
    int lane = c & 63;
    int kbase = s * 32 + (lane >> 4) * 8;
    int n     = nb * 16 + (lane & 15);
    __bf16* dst = out + (size_t)wi * WPK_ELEMS + (size_t)c * 8;
    #pragma unroll
    for (int j = 0; j < 8; ++j) {
        int k = kbase + j;
        float v = (k < DIMN && n < DIMN) ? W[k * DIMN + n] : 0.0f;
        dst[j] = (__bf16)v;
    }
}

// ---------------- G1: Out = A1@W1 + A2@W2 ; BM=64 (R0 proven config) ----------------
// R3 lesson: BM=128 blew unified regs (~280) -> 1 wave/SIMD; this kernel is
// latency-bound, occupancy >> per-wave weight reuse.
__launch_bounds__(256)
__global__ void gemm_dual(const __bf16* __restrict__ A1, const __bf16* __restrict__ W1,
                          const __bf16* __restrict__ A2, const __bf16* __restrict__ W2,
                          __bf16* __restrict__ OutR, __bf16* __restrict__ OutF, int M)
{
    const int tid  = threadIdx.x;
    const int w    = tid >> 6;
    const int lane = tid & 63;
    const int rlo  = lane & 15;
    const int g    = lane >> 4;
    const int nb0  = blockIdx.x * 4;
    const int bm   = blockIdx.x * 64;

    __shared__ __bf16 T[64][264];

    v4f acc[4][4];
    #pragma unroll
    for (int mi = 0; mi < 4; ++mi)
        #pragma unroll
        for (int ni = 0; ni < 4; ++ni)
            acc[mi][ni] = (v4f){0.f, 0.f, 0.f, 0.f};

    const __bf16* w1b = W1 + (size_t)(w * 4 * 64 + lane) * 8;
    const __bf16* w2b = W2 + (size_t)(w * 4 * 64 + lane) * 8;

    for (int s = 0; s < KSTEPS; ++s) {
        v8bf b1[4], b2[4];
        #pragma unroll
        for (int ni = 0; ni < 4; ++ni) {
            b1[ni] = *(const v8bf*)(w1b + ((size_t)s * NB16 * 64 + ni * 64) * 8);
            b2[ni] = *(const v8bf*)(w2b + ((size_t)s * NB16 * 64 + ni * 64) * 8);
        }
        #pragma unroll
        for (int mi = 0; mi < 4; ++mi) {
            size_t aoff = (size_t)((nb0 + mi) * KSTEPS + s) * 512 + lane * 8;
            v8bf a1 = *(const v8bf*)(A1 + aoff);
            v8bf a2 = *(const v8bf*)(A2 + aoff);
            #pragma unroll
            for (int ni = 0; ni < 4; ++ni)
                acc[mi][ni] = __builtin_amdgcn_mfma_f32_16x16x32_bf16(a1, b1[ni], acc[mi][ni], 0, 0, 0);
            #pragma unroll
            for (int ni = 0; ni < 4; ++ni)
                acc[mi][ni] = __builtin_amdgcn_mfma_f32_16x16x32_bf16(a2, b2[ni], acc[mi][ni], 0, 0, 0);
        }
    }

    // D -> LDS tile (row_local = mi*16 + g*4 + reg, col = w*64 + ni*16 + rlo)
    #pragma unroll
    for (int mi = 0; mi < 4; ++mi)
        #pragma unroll
        for (int reg = 0; reg < 4; ++reg)
            #pragma unroll
            for (int ni = 0; ni < 4; ++ni)
                T[mi * 16 + g * 4 + reg][w * 64 + ni * 16 + rlo] = (__bf16)acc[mi][ni][reg];
    __syncthreads();

    // frag emit: 4 nb * 7 s * 64 slots = 1792
    #pragma unroll
    for (int j = 0; j < 7; ++j) {
        int it = tid + j * 256;
        int slot = it & 63;
        int q = it >> 6;          // 0..27
        int s = q % 7, nb = q / 7;
        *(v8bf*)(OutF + (size_t)((nb0 + nb) * KSTEPS + s) * 512 + slot * 8) =
            *(const v8bf*)&T[nb * 16 + (slot & 15)][s * 32 + (slot >> 4) * 8];
    }
    // row emit: 64 rows * 25 chunks = 1600
    #pragma unroll
    for (int j = 0; j < 7; ++j) {
        int it = tid + j * 256;
        if (it < 1600) {
            int row = it / 25, ch = it - row * 25;
            int gr = bm + row;
            if (gr < M)
                *(v8bf*)(OutR + (size_t)gr * DIMN + ch * 8) = *(const v8bf*)&T[row][ch * 8];
        }
    }
}

// ---------------- G2 mega: cur = l2norm(A1@W1 + A2@W2); gate = sigmoid(A3@W3 + bias);
//                  h' = l2norm(gate*cur + (1-gate)*h)
// R3 redesign: BM=32 kept, but 8 waves x (ni=2) instead of 4 waves x (ni=4).
// Per-wave regs: acc 8 v4f (32 AGPR) + 6 B-stage + 3 A-stage v8bf -> ~100 unified,
// 2 blocks/CU = 4 waves/SIMD (was 3). Latency-bound kernel: occupancy is the lever
// (R0 28.6%->131us, R3 10%->320us monotone). A-loads duplicate 2x but L1-resident.
__launch_bounds__(512)
__global__ void gemm_mega(const __bf16* __restrict__ A1, const __bf16* __restrict__ W1,
                          const __bf16* __restrict__ A2, const __bf16* __restrict__ W2,
                          const __bf16* __restrict__ A3, const __bf16* __restrict__ W3,
                          const float* __restrict__ Bias,
                          __bf16* __restrict__ HR, __bf16* __restrict__ HF,
                          float* __restrict__ DoutF, int M, int finalStep)
{
    const int tid  = threadIdx.x;
    const int w    = tid >> 6;          // 0..7
    const int lane = tid & 63;
    const int rlo  = lane & 15;
    const int g    = lane >> 4;
    const int nb0  = blockIdx.x * 2;
    const int bm   = blockIdx.x * 32;

    __shared__ __bf16 T[32][264];
    __shared__ float  rsq1[32][8];
    __shared__ float  rsq2[32][8];

    v4f acc1[2][2], acc2[2][2];
    #pragma unroll
    for (int mi = 0; mi < 2; ++mi)
        #pragma unroll
        for (int ni = 0; ni < 2; ++ni) {
            acc1[mi][ni] = (v4f){0.f, 0.f, 0.f, 0.f};
            acc2[mi][ni] = (v4f){0.f, 0.f, 0.f, 0.f};
        }

    // wave w covers col blocks nb = w*2 + ni  (cols w*32 + ni*16 + rlo)
    const __bf16* w1b = W1 + (size_t)(w * 2 * 64 + lane) * 8;
    const __bf16* w2b = W2 + (size_t)(w * 2 * 64 + lane) * 8;
    const __bf16* w3b = W3 + (size_t)(w * 2 * 64 + lane) * 8;

    for (int s = 0; s < KSTEPS; ++s) {
        v8bf b1[2], b2[2], b3[2];
        #pragma unroll
        for (int ni = 0; ni < 2; ++ni) {
            size_t bo = ((size_t)s * NB16 * 64 + ni * 64) * 8;
            b1[ni] = *(const v8bf*)(w1b + bo);
            b2[ni] = *(const v8bf*)(w2b + bo);
            b3[ni] = *(const v8bf*)(w3b + bo);
        }
        #pragma unroll
        for (int mi = 0; mi < 2; ++mi) {
            size_t aoff = (size_t)((nb0 + mi) * KSTEPS + s) * 512 + lane * 8;
            v8bf a1 = *(const v8bf*)(A1 + aoff);
            v8bf a2 = *(const v8bf*)(A2 + aoff);
            v8bf a3 = *(const v8bf*)(A3 + aoff);
            #pragma unroll
            for (int ni = 0; ni < 2; ++ni)
                acc1[mi][ni] = __builtin_amdgcn_mfma_f32_16x16x32_bf16(a1, b1[ni], acc1[mi][ni], 0, 0, 0);
            #pragma unroll
            for (int ni = 0; ni < 2; ++ni)
                acc1[mi][ni] = __builtin_amdgcn_mfma_f32_16x16x32_bf16(a2, b2[ni], acc1[mi][ni], 0, 0, 0);
            #pragma unroll
            for (int ni = 0; ni < 2; ++ni)
                acc2[mi][ni] = __builtin_amdgcn_mfma_f32_16x16x32_bf16(a3, b3[ni], acc2[mi][ni], 0, 0, 0);
        }
    }

    // cur row sums-of-squares (cols >= 200 are zero via weight padding)
    #pragma unroll
    for (int mi = 0; mi < 2; ++mi)
        #pragma unroll
        for (int reg = 0; reg < 4; ++reg) {
            float ss = 0.0f;
            #pragma unroll
            for (int ni = 0; ni < 2; ++ni) ss += acc1[mi][ni][reg] * acc1[mi][ni][reg];
            ss += __shfl_xor(ss, 1, 64);
            ss += __shfl_xor(ss, 2, 64);
            ss += __shfl_xor(ss, 4, 64);
            ss += __shfl_xor(ss, 8, 64);
            if (rlo == 0) rsq1[mi * 16 + g * 4 + reg][w] = ss;
        }
    // stage h rows into T (buffer reused; overwritten only after blend completes)
    #pragma unroll
    for (int j = 0; j < 2; ++j) {
        int it = tid + j * 512;
        if (it < 800) {
            int row = it / 25, ch = it - row * 25;
            int gr = bm + row;
            v8bf hv = {};
            if (gr < M) hv = *(const v8bf*)(HR + (size_t)gr * DIMN + ch * 8);
            *(v8bf*)&T[row][ch * 8] = hv;
        }
    }
    __syncthreads();

    // blend: v = gate*cur + (1-gate)*h  (store into acc1), second row reduce
    #pragma unroll
    for (int mi = 0; mi < 2; ++mi)
        #pragma unroll
        for (int reg = 0; reg < 4; ++reg) {
            int rl = mi * 16 + g * 4 + reg;
            float tot = rsq1[rl][0] + rsq1[rl][1] + rsq1[rl][2] + rsq1[rl][3]
                      + rsq1[rl][4] + rsq1[rl][5] + rsq1[rl][6] + rsq1[rl][7];
            float sc1 = 1.0f / fmaxf(sqrtf(tot), 1e-12f);
            float ss = 0.0f;
            #pragma unroll
            for (int ni = 0; ni < 2; ++ni) {
                int c = w * 32 + ni * 16 + rlo;
                float v = 0.0f;
                if (c < DIMN) {
                    float cur = acc1[mi][ni][reg] * sc1;
                    float gg  = 1.0f / (1.0f + __expf(-(acc2[mi][ni][reg] + Bias[c])));
                    float hh  = (float)T[rl][c];
                    v = gg * cur + (1.0f - gg) * hh;
                }
                acc1[mi][ni][reg] = v;
                ss += v * v;
            }
            ss += __shfl_xor(ss, 1, 64);
            ss += __shfl_xor(ss, 2, 64);
            ss += __shfl_xor(ss, 4, 64);
            ss += __shfl_xor(ss, 8, 64);
            if (rlo == 0) rsq2[rl][w] = ss;
        }
    __syncthreads();

    // final scale -> T (overwrites staged h; all h reads completed before the barrier above)
    #pragma unroll
    for (int mi = 0; mi < 2; ++mi)
        #pragma unroll
        for (int reg = 0; reg < 4; ++reg) {
            int rl = mi * 16 + g * 4 + reg;
            float tot = rsq2[rl][0] + rsq2[rl][1] + rsq2[rl][2] + rsq2[rl][3]
                      + rsq2[rl][4] + rsq2[rl][5] + rsq2[rl][6] + rsq2[rl][7];
            float sc2 = 1.0f / fmaxf(sqrtf(tot), 1e-12f);
            #pragma unroll
            for (int ni = 0; ni < 2; ++ni) {
                int c = w * 32 + ni * 16 + rlo;
                T[rl][c] = (__bf16)(acc1[mi][ni][reg] * sc2);
            }
        }
    __syncthreads();

    if (!finalStep) {
        // h' rows: 32 rows * 25 chunks = 800
        #pragma unroll
        for (int j = 0; j < 2; ++j) {
            int it = tid + j * 512;
            if (it < 800) {
                int row = it / 25, ch = it - row * 25;
                int gr = bm + row;
                if (gr < M)
                    *(v8bf*)(HR + (size_t)gr * DIMN + ch * 8) = *(const v8bf*)&T[row][ch * 8];
            }
        }
        // h' frag: 2 nb * 7 s * 64 slots = 896
        #pragma unroll
        for (int j = 0; j < 2; ++j) {
            int it = tid + j * 512;
            if (it < 896) {
                int slot = it & 63;
                int q = it >> 6;          // 0..13
                int s = q % 7, nb = q / 7;
                *(v8bf*)(HF + (size_t)((nb0 + nb) * KSTEPS + s) * 512 + slot * 8) =
                    *(const v8bf*)&T[nb * 16 + (slot & 15)][s * 32 + (slot >> 4) * 8];
            }
        }
    } else {
        // fp32 output rows
        #pragma unroll
        for (int j = 0; j < 2; ++j) {
            int it = tid + j * 512;
            if (it < 800) {
                int row = it / 25, ch = it - row * 25;
                int gr = bm + row;
                if (gr < M) {
                    v8bf o = *(const v8bf*)&T[row][ch * 8];
                    float4* q0 = (float4*)(DoutF + (size_t)gr * DIMN + ch * 8);
                    q0[0] = make_float4((float)o[0], (float)o[1], (float)o[2], (float)o[3]);
                    q0[1] = make_float4((float)o[4], (float)o[5], (float)o[6], (float)o[7]);
                }
            }
        }
    }
}

extern "C" void kernel_launch(void* const* d_in, const int* in_sizes, int n_in,
                              void* d_out, int out_size, void* d_ws, size_t ws_size,
                              hipStream_t stream)
{
    const int*   edges = (const int*)  d_in[0];
    const float* ent   = (const float*)d_in[1];
    const float* relE  = (const float*)d_in[2];
    const float* Wm1   = (const float*)d_in[3];
    const float* Wl1   = (const float*)d_in[4];
    const float* Wm2   = (const float*)d_in[5];
    const float* Wl2   = (const float*)d_in[6];
    const float* Wtg   = (const float*)d_in[7];
    const float* bias  = (const float*)d_in[8];
    float* Dout = (float*)d_out;

    const size_t NM    = (size_t)NNODES * DIMN;
    const size_t FRAGN = (size_t)NBN * FRAG_STRIDE;

    __bf16* hR   = (__bf16*)d_ws;                      // h row-major (gather + mega-epilogue)
    __bf16* hF   = hR + NM;                            // h fragment (GEMM-A)
    __bf16* SF   = hF + FRAGN;                         // S1/S2 fragment
    __bf16* BR   = SF + FRAGN;                         // layer-1 out rows (gather)
    __bf16* BF   = BR + NM;                            // layer-1 out fragment
    __bf16* RnR  = BF + FRAGN;                         // normalized relations rows
    __bf16* Wpk  = RnR + (size_t)NREL * DIMN;          // 5 packed weights
    __bf16* pWm1 = Wpk + 0 * (size_t)WPK_ELEMS;
    __bf16* pWl1 = Wpk + 1 * (size_t)WPK_ELEMS;
    __bf16* pWm2 = Wpk + 2 * (size_t)WPK_ELEMS;
    __bf16* pWl2 = Wpk + 3 * (size_t)WPK_ELEMS;
    __bf16* pWtg = Wpk + 4 * (size_t)WPK_ELEMS;
    int*  counts = (int*)(Wpk + 5 * (size_t)WPK_ELEMS);
    int2* sorted = (int2*)(counts + NNODES);
    int*  offs   = (int*)(sorted + NEDGES);
    int*  bsum   = offs + (NNODES + 1);
    int*  stmp   = bsum + 256;

    dim3 blk(256);
    const int GD = (NNODES + 63) / 64;      // 1563 (dual, BM=64)
    const int GM = (NNODES + 31) / 32;      // 3125 (mega, BM=32, 512 thr)
    dim3 ngrid32((NNODES * 32 + 255) / 256);
    dim3 rgrid32((NREL * 32 + 255) / 256);
    dim3 agrid((NNODES + 3) / 4);
    dim3 egrid((NEDGES + 255) / 256);
    const int NSB = (NNODES + SCAN_B - 1) / SCAN_B;

    pack_w<<<dim3((5 * KSTEPS * NB16 * 64 + 255) / 256), blk, 0, stream>>>(Wm1, Wl1, Wm2, Wl2, Wtg, Wpk);
    l2norm_pro<<<ngrid32, blk, 0, stream>>>(ent, hR, hF, NNODES);
    l2norm_pro<<<rgrid32, blk, 0, stream>>>(relE, RnR, nullptr, NREL);

    for (int t = 0; t < 3; ++t) {
        const int* ed = edges + (size_t)t * NEDGES * 3;
        // ---- CSR build ----
        hipMemsetAsync(counts, 0, NNODES * sizeof(int), stream);
        edge_hist<<<egrid, blk, 0, stream>>>(ed, counts, NEDGES);
        scan1<<<NSB, SCAN_B, 0, stream>>>(counts, stmp, bsum, NNODES);
        scan2<<<1, 128, 0, stream>>>(bsum, NSB);
        scan3<<<NSB, SCAN_B, 0, stream>>>(stmp, bsum, offs, NNODES);
        hipMemsetAsync(counts, 0, NNODES * sizeof(int), stream);   // cursor
        edge_fill<<<egrid, blk, 0, stream>>>(ed, offs, counts, sorted, NEDGES);
        // ---- layer 1 (linearity: aggregate in h-space, then fused dual-stream GEMM) ----
        agg_S<<<agrid, blk, 0, stream>>>(offs, sorted, hR, RnR, SF, NNODES);
        gemm_dual<<<GD, blk, 0, stream>>>(SF, pWm1, hF, pWl1, BR, BF, NNODES);
        // ---- layer 2 + gate + blend + norms (mega) ----
        agg_S<<<agrid, blk, 0, stream>>>(offs, sorted, BR, RnR, SF, NNODES);
        gemm_mega<<<GM, dim3(512), 0, stream>>>(SF, pWm2, BF, pWl2, hF, pWtg, bias,
                                                hR, hF, Dout, NNODES, (t == 2) ? 1 : 0);
    }
}

// Round 5
// 994.685 us; speedup vs baseline: 1.7468x; 1.0449x over previous
//
#include <hip/hip_runtime.h>
#include <math.h>

#define DIMN   200
#define NNODES 100000
#define NREL   500
#define NEDGES 200000
#define KSTEPS 7            // K padded 200 -> 224 = 7*32
#define NB16   16           // N padded 200 -> 256
#define WPK_ELEMS (KSTEPS * NB16 * 64 * 8)   // 57344 bf16 per weight
#define SCAN_B 1024
#define NBN    6252         // node fragment blocks (16 rows each)
#define FRAG_STRIDE 3584    // elems per frag block = KSTEPS*512

typedef float  v4f  __attribute__((ext_vector_type(4)));
typedef __bf16 v8bf __attribute__((ext_vector_type(8)));

// A-fragment layout: element (row r in block nb, k = c*8+j) at
//   (nb*KSTEPS + c/4)*512 + (c%4)*128 + r*8 + j        (c = chunk 0..27)
__device__ __forceinline__ size_t frag_chunk(int nb, int c, int r) {
    return (size_t)(nb * KSTEPS + (c >> 2)) * 512 + (size_t)((c & 3) * 128 + r * 8);
}

// ---------------- prologue l2norm: fp32 rows -> bf16 row + optional bf16 frag ----------------
__launch_bounds__(256)
__global__ void l2norm_pro(const float* __restrict__ in, __bf16* __restrict__ outR,
                           __bf16* __restrict__ outF, int nrows)
{
    int idx  = blockIdx.x * 256 + threadIdx.x;
    int node = idx >> 5;
    int ch   = idx & 31;
    if (node >= nrows) return;
    float v[8] = {};
    if (ch < 25) {
        const float4* p = (const float4*)(in + (size_t)node * DIMN + ch * 8);
        float4 f0 = p[0], f1 = p[1];
        v[0]=f0.x; v[1]=f0.y; v[2]=f0.z; v[3]=f0.w;
        v[4]=f1.x; v[5]=f1.y; v[6]=f1.z; v[7]=f1.w;
    }
    float ss = 0.0f;
    #pragma unroll
    for (int k = 0; k < 8; ++k) ss += v[k] * v[k];
    #pragma unroll
    for (int off = 16; off; off >>= 1) ss += __shfl_xor(ss, off, 64);
    float s = 1.0f / fmaxf(sqrtf(ss), 1e-12f);
    #pragma unroll
    for (int k = 0; k < 8; ++k) v[k] *= s;
    if (ch < 25) {
        v8bf o;
        #pragma unroll
        for (int k = 0; k < 8; ++k) o[k] = (__bf16)v[k];
        *(v8bf*)(outR + (size_t)node * DIMN + ch * 8) = o;
    }
    if (outF && ch < 28) {
        v8bf o;
        #pragma unroll
        for (int k = 0; k < 8; ++k) o[k] = (ch < 25) ? (__bf16)v[k] : (__bf16)0.0f;
        *(v8bf*)(outF + frag_chunk(node >> 4, ch, node & 15)) = o;
    }
}

// ---------------- CSR build ----------------
__launch_bounds__(256)
__global__ void edge_hist(const int* __restrict__ edges, int* __restrict__ counts, int nedges)
{
    int e = blockIdx.x * 256 + threadIdx.x;
    if (e < nedges) atomicAdd(&counts[edges[e * 3 + 2]], 1);
}

__launch_bounds__(SCAN_B)
__global__ void scan1(const int* __restrict__ counts, int* __restrict__ tmp,
                      int* __restrict__ bsum, int n)
{
    __shared__ int sh[SCAN_B];
    int i = blockIdx.x * SCAN_B + threadIdx.x;
    int v = (i < n) ? counts[i] : 0;
    sh[threadIdx.x] = v;
    __syncthreads();
    for (int off = 1; off < SCAN_B; off <<= 1) {
        int t = (threadIdx.x >= off) ? sh[threadIdx.x - off] : 0;
        __syncthreads();
        sh[threadIdx.x] += t;
        __syncthreads();
    }
    if (i < n) tmp[i] = sh[threadIdx.x];
    if (threadIdx.x == SCAN_B - 1) bsum[blockIdx.x] = sh[threadIdx.x];
}

__launch_bounds__(128)
__global__ void scan2(int* __restrict__ bsum, int nb)
{
    __shared__ int sh[128];
    int v = (threadIdx.x < nb) ? bsum[threadIdx.x] : 0;
    sh[threadIdx.x] = v;
    __syncthreads();
    for (int off = 1; off < 128; off <<= 1) {
        int t = (threadIdx.x >= off) ? sh[threadIdx.x - off] : 0;
        __syncthreads();
        sh[threadIdx.x] += t;
        __syncthreads();
    }
    if (threadIdx.x < nb) bsum[threadIdx.x] = sh[threadIdx.x] - v;
}

__launch_bounds__(SCAN_B)
__global__ void scan3(const int* __restrict__ tmp, const int* __restrict__ bsum,
                      int* __restrict__ offs, int n)
{
    int i = blockIdx.x * SCAN_B + threadIdx.x;
    if (i < n) offs[i + 1] = tmp[i] + bsum[blockIdx.x];
    if (i == 0) offs[0] = 0;
}

__launch_bounds__(256)
__global__ void edge_fill(const int* __restrict__ edges, const int* __restrict__ offs,
                          int* __restrict__ cursor, int2* __restrict__ sorted, int nedges)
{
    int e = blockIdx.x * 256 + threadIdx.x;
    if (e >= nedges) return;
    int s = edges[e * 3 + 0];
    int r = edges[e * 3 + 1];
    int d = edges[e * 3 + 2];
    int p = offs[d] + atomicAdd(&cursor[d], 1);
    sorted[p] = make_int2(s, r);
}

// ---------------- aggregate in h-space: S = segsum(x[src] + r[rel]) / max(deg,1) ----------------
__launch_bounds__(256)
__global__ void agg_S(const int* __restrict__ offs, const int2* __restrict__ sorted,
                      const __bf16* __restrict__ XR, const __bf16* __restrict__ RnR,
                      __bf16* __restrict__ SF, int nnodes)
{
    int wave = (int)((blockIdx.x * blockDim.x + threadIdx.x) >> 6);
    int lane = threadIdx.x & 63;
    if (wave >= nnodes) return;
    int beg = offs[wave], end = offs[wave + 1];
    int ch = lane & 31;
    bool act = ch < 25;

    float acc[8] = {};
    for (int e = beg; e < end; ++e) {
        int2 sr = sorted[e];
        const __bf16* base = (lane < 32) ? (XR + (size_t)sr.x * DIMN)
                                         : (RnR + (size_t)sr.y * DIMN);
        v8bf v = {};
        if (act) v = *(const v8bf*)(base + ch * 8);
        #pragma unroll
        for (int k = 0; k < 8; ++k) acc[k] += (float)v[k];
    }
    #pragma unroll
    for (int k = 0; k < 8; ++k) acc[k] += __shfl_xor(acc[k], 32, 64);

    float rdeg = 1.0f / fmaxf((float)(end - beg), 1.0f);
    if (lane < 32 && ch < 28) {
        v8bf o;
        #pragma unroll
        for (int k = 0; k < 8; ++k) o[k] = act ? (__bf16)(acc[k] * rdeg) : (__bf16)0.0f;
        *(v8bf*)(SF + frag_chunk(wave >> 4, ch, wave & 15)) = o;
    }
}

// ---------------- weight pack: fp32 W[200x200] -> bf16 MFMA-B-fragment-linear ----------------
__launch_bounds__(256)
__global__ void pack_w(const float* __restrict__ W0, const float* __restrict__ W1,
                       const float* __restrict__ W2, const float* __restrict__ W3,
                       const float* __restrict__ W4, __bf16* __restrict__ out)
{
    int id = blockIdx.x * 256 + threadIdx.x;
    const int nchunk = KSTEPS * NB16 * 64;        // 7168
    if (id >= 5 * nchunk) return;
    int wi = id / nchunk;
    int c  = id % nchunk;
    const float* W = wi == 0 ? W0 : wi == 1 ? W1 : wi == 2 ? W2 : wi == 3 ? W3 : W4;
    int s    = c >> 10;
    int nb   = (c & 1023) >> 6;
    int lane = c & 63;
    int kbase = s * 32 + (lane >> 4) * 8;
    int n     = nb * 16 + (lane & 15);
    __bf16* dst = out + (size_t)wi * WPK_ELEMS + (size_t)c * 8;
    #pragma unroll
    for (int j = 0; j < 8; ++j) {
        int k = kbase + j;
        float v = (k < DIMN && n < DIMN) ? W[k * DIMN + n] : 0.0f;
        dst[j] = (__bf16)v;
    }
}

// ---------------- G1: Out = A1@W1 + A2@W2 ; BM=64, 8 waves x ni=2 (R4-mega structure) ----------------
// R4 lesson replicated: 8 narrow waves (acc 8 v4f = 32 AGPR) instead of 4 wide ones.
__launch_bounds__(512)
__global__ void gemm_dual(const __bf16* __restrict__ A1, const __bf16* __restrict__ W1,
                          const __bf16* __restrict__ A2, const __bf16* __restrict__ W2,
                          __bf16* __restrict__ OutR, __bf16* __restrict__ OutF, int M)
{
    const int tid  = threadIdx.x;
    const int w    = tid >> 6;          // 0..7
    const int lane = tid & 63;
    const int rlo  = lane & 15;
    const int g    = lane >> 4;
    const int nb0  = blockIdx.x * 4;
    const int bm   = blockIdx.x * 64;

    __shared__ __bf16 T[64][264];

    v4f acc[4][2];
    #pragma unroll
    for (int mi = 0; mi < 4; ++mi)
        #pragma unroll
        for (int ni = 0; ni < 2; ++ni)
            acc[mi][ni] = (v4f){0.f, 0.f, 0.f, 0.f};

    // wave w covers col blocks w*2 + ni (cols w*32 + ni*16 + rlo)
    const __bf16* w1b = W1 + (size_t)(w * 2 * 64 + lane) * 8;
    const __bf16* w2b = W2 + (size_t)(w * 2 * 64 + lane) * 8;

    #pragma unroll
    for (int s = 0; s < KSTEPS; ++s) {
        v8bf b1[2], b2[2];
        #pragma unroll
        for (int ni = 0; ni < 2; ++ni) {
            size_t bo = ((size_t)s * NB16 * 64 + ni * 64) * 8;
            b1[ni] = *(const v8bf*)(w1b + bo);
            b2[ni] = *(const v8bf*)(w2b + bo);
        }
        #pragma unroll
        for (int mi = 0; mi < 4; ++mi) {
            size_t aoff = (size_t)((nb0 + mi) * KSTEPS + s) * 512 + lane * 8;
            v8bf a1 = *(const v8bf*)(A1 + aoff);
            v8bf a2 = *(const v8bf*)(A2 + aoff);
            #pragma unroll
            for (int ni = 0; ni < 2; ++ni)
                acc[mi][ni] = __builtin_amdgcn_mfma_f32_16x16x32_bf16(a1, b1[ni], acc[mi][ni], 0, 0, 0);
            #pragma unroll
            for (int ni = 0; ni < 2; ++ni)
                acc[mi][ni] = __builtin_amdgcn_mfma_f32_16x16x32_bf16(a2, b2[ni], acc[mi][ni], 0, 0, 0);
        }
    }

    // D -> LDS tile (row = mi*16 + g*4 + reg, col = w*32 + ni*16 + rlo)
    #pragma unroll
    for (int mi = 0; mi < 4; ++mi)
        #pragma unroll
        for (int reg = 0; reg < 4; ++reg)
            #pragma unroll
            for (int ni = 0; ni < 2; ++ni)
                T[mi * 16 + g * 4 + reg][w * 32 + ni * 16 + rlo] = (__bf16)acc[mi][ni][reg];
    __syncthreads();

    // frag emit: 4 nb * 7 s * 64 slots = 1792
    #pragma unroll
    for (int j = 0; j < 4; ++j) {
        int it = tid + j * 512;
        if (it < 1792) {
            int slot = it & 63;
            int q = it >> 6;          // 0..27
            int s = q % 7, nb = q / 7;
            *(v8bf*)(OutF + (size_t)((nb0 + nb) * KSTEPS + s) * 512 + slot * 8) =
                *(const v8bf*)&T[nb * 16 + (slot & 15)][s * 32 + (slot >> 4) * 8];
        }
    }
    // row emit: 64 rows * 25 chunks = 1600
    #pragma unroll
    for (int j = 0; j < 4; ++j) {
        int it = tid + j * 512;
        if (it < 1600) {
            int row = it / 25, ch = it - row * 25;
            int gr = bm + row;
            if (gr < M)
                *(v8bf*)(OutR + (size_t)gr * DIMN + ch * 8) = *(const v8bf*)&T[row][ch * 8];
        }
    }
}

// ---------------- G2 mega: cur = l2norm(A1@W1 + A2@W2); gate = sigmoid(A3@W3 + bias);
//                  h' = l2norm(gate*cur + (1-gate)*h)
// R5: LDS-staged A. All 42 1KB A-chunks (3 streams x 2 nb x 7 s) staged once per
// block; K-loop reads A via ds_read_b128 (conflict-free lane*16B), only B-loads
// stay global (compile-time offsets -> hoistable). Removes 8x A duplication through
// L1 and A's per-step L2 latency. T aliases As (disjoint use, barrier-guarded);
// LDS 44KB -> 3 blocks/CU = 24 waves (same 75% occupancy as R4).
__launch_bounds__(512)
__global__ void gemm_mega(const __bf16* __restrict__ A1, const __bf16* __restrict__ W1,
                          const __bf16* __restrict__ A2, const __bf16* __restrict__ W2,
                          const __bf16* __restrict__ A3, const __bf16* __restrict__ W3,
                          const float* __restrict__ Bias,
                          __bf16* __restrict__ HR, __bf16* __restrict__ HF,
                          float* __restrict__ DoutF, int M, int finalStep)
{
    const int tid  = threadIdx.x;
    const int w    = tid >> 6;          // 0..7
    const int lane = tid & 63;
    const int rlo  = lane & 15;
    const int g    = lane >> 4;
    const int nb0  = blockIdx.x * 2;
    const int bm   = blockIdx.x * 32;

    __shared__ __bf16 As[42][512];      // 43KB; chunk c = stream*14 + nb*7 + s
    __shared__ float  rsq1[32][8];
    __shared__ float  rsq2[32][8];
    __bf16 (*T)[264] = (__bf16(*)[264])&As[0][0];   // 16.9KB alias, used after K-loop

    v4f acc1[2][2], acc2[2][2];
    #pragma unroll
    for (int mi = 0; mi < 2; ++mi)
        #pragma unroll
        for (int ni = 0; ni < 2; ++ni) {
            acc1[mi][ni] = (v4f){0.f, 0.f, 0.f, 0.f};
            acc2[mi][ni] = (v4f){0.f, 0.f, 0.f, 0.f};
        }

    // ---- stage A: 42 chunks of 1KB, wave-uniform chunk per issue ----
    #pragma unroll
    for (int j = 0; j < 6; ++j) {
        int c = w + j * 8;
        if (c < 42) {
            int stream = c / 14;
            int rem    = c - stream * 14;
            int nb     = rem / 7;
            int s      = rem - nb * 7;
            const __bf16* Asrc = stream == 0 ? A1 : stream == 1 ? A2 : A3;
            *(v8bf*)&As[c][lane * 8] =
                *(const v8bf*)(Asrc + (size_t)((nb0 + nb) * KSTEPS + s) * 512 + lane * 8);
        }
    }

    const __bf16* w1b = W1 + (size_t)(w * 2 * 64 + lane) * 8;
    const __bf16* w2b = W2 + (size_t)(w * 2 * 64 + lane) * 8;
    const __bf16* w3b = W3 + (size_t)(w * 2 * 64 + lane) * 8;
    __syncthreads();

    #pragma unroll
    for (int s = 0; s < KSTEPS; ++s) {
        v8bf b1[2], b2[2], b3[2];
        #pragma unroll
        for (int ni = 0; ni < 2; ++ni) {
            size_t bo = ((size_t)s * NB16 * 64 + ni * 64) * 8;
            b1[ni] = *(const v8bf*)(w1b + bo);
            b2[ni] = *(const v8bf*)(w2b + bo);
            b3[ni] = *(const v8bf*)(w3b + bo);
        }
        #pragma unroll
        for (int mi = 0; mi < 2; ++mi) {
            v8bf a1 = *(const v8bf*)&As[ 0 + mi * 7 + s][lane * 8];
            v8bf a2 = *(const v8bf*)&As[14 + mi * 7 + s][lane * 8];
            v8bf a3 = *(const v8bf*)&As[28 + mi * 7 + s][lane * 8];
            #pragma unroll
            for (int ni = 0; ni < 2; ++ni)
                acc1[mi][ni] = __builtin_amdgcn_mfma_f32_16x16x32_bf16(a1, b1[ni], acc1[mi][ni], 0, 0, 0);
            #pragma unroll
            for (int ni = 0; ni < 2; ++ni)
                acc1[mi][ni] = __builtin_amdgcn_mfma_f32_16x16x32_bf16(a2, b2[ni], acc1[mi][ni], 0, 0, 0);
            #pragma unroll
            for (int ni = 0; ni < 2; ++ni)
                acc2[mi][ni] = __builtin_amdgcn_mfma_f32_16x16x32_bf16(a3, b3[ni], acc2[mi][ni], 0, 0, 0);
        }
    }

    // cur row sums-of-squares (cols >= 200 are zero via weight padding)
    #pragma unroll
    for (int mi = 0; mi < 2; ++mi)
        #pragma unroll
        for (int reg = 0; reg < 4; ++reg) {
            float ss = 0.0f;
            #pragma unroll
            for (int ni = 0; ni < 2; ++ni) ss += acc1[mi][ni][reg] * acc1[mi][ni][reg];
            ss += __shfl_xor(ss, 1, 64);
            ss += __shfl_xor(ss, 2, 64);
            ss += __shfl_xor(ss, 4, 64);
            ss += __shfl_xor(ss, 8, 64);
            if (rlo == 0) rsq1[mi * 16 + g * 4 + reg][w] = ss;
        }
    __syncthreads();   // all waves done reading As before it is overwritten as T

    // stage h rows into T (aliases As)
    #pragma unroll
    for (int j = 0; j < 2; ++j) {
        int it = tid + j * 512;
        if (it < 800) {
            int row = it / 25, ch = it - row * 25;
            int gr = bm + row;
            v8bf hv = {};
            if (gr < M) hv = *(const v8bf*)(HR + (size_t)gr * DIMN + ch * 8);
            *(v8bf*)&T[row][ch * 8] = hv;
        }
    }
    __syncthreads();

    // blend: v = gate*cur + (1-gate)*h  (store into acc1), second row reduce
    #pragma unroll
    for (int mi = 0; mi < 2; ++mi)
        #pragma unroll
        for (int reg = 0; reg < 4; ++reg) {
            int rl = mi * 16 + g * 4 + reg;
            float tot = rsq1[rl][0] + rsq1[rl][1] + rsq1[rl][2] + rsq1[rl][3]
                      + rsq1[rl][4] + rsq1[rl][5] + rsq1[rl][6] + rsq1[rl][7];
            float sc1 = 1.0f / fmaxf(sqrtf(tot), 1e-12f);
            float ss = 0.0f;
            #pragma unroll
            for (int ni = 0; ni < 2; ++ni) {
                int c = w * 32 + ni * 16 + rlo;
                float v = 0.0f;
                if (c < DIMN) {
                    float cur = acc1[mi][ni][reg] * sc1;
                    float gg  = 1.0f / (1.0f + __expf(-(acc2[mi][ni][reg] + Bias[c])));
                    float hh  = (float)T[rl][c];
                    v = gg * cur + (1.0f - gg) * hh;
                }
                acc1[mi][ni][reg] = v;
                ss += v * v;
            }
            ss += __shfl_xor(ss, 1, 64);
            ss += __shfl_xor(ss, 2, 64);
            ss += __shfl_xor(ss, 4, 64);
            ss += __shfl_xor(ss, 8, 64);
            if (rlo == 0) rsq2[rl][w] = ss;
        }
    __syncthreads();

    // final scale -> T (overwrites staged h; all h reads completed before barrier above)
    #pragma unroll
    for (int mi = 0; mi < 2; ++mi)
        #pragma unroll
        for (int reg = 0; reg < 4; ++reg) {
            int rl = mi * 16 + g * 4 + reg;
            float tot = rsq2[rl][0] + rsq2[rl][1] + rsq2[rl][2] + rsq2[rl][3]
                      + rsq2[rl][4] + rsq2[rl][5] + rsq2[rl][6] + rsq2[rl][7];
            float sc2 = 1.0f / fmaxf(sqrtf(tot), 1e-12f);
            #pragma unroll
            for (int ni = 0; ni < 2; ++ni) {
                int c = w * 32 + ni * 16 + rlo;
                T[rl][c] = (__bf16)(acc1[mi][ni][reg] * sc2);
            }
        }
    __syncthreads();

    if (!finalStep) {
        // h' rows: 32 rows * 25 chunks = 800
        #pragma unroll
        for (int j = 0; j < 2; ++j) {
            int it = tid + j * 512;
            if (it < 800) {
                int row = it / 25, ch = it - row * 25;
                int gr = bm + row;
                if (gr < M)
                    *(v8bf*)(HR + (size_t)gr * DIMN + ch * 8) = *(const v8bf*)&T[row][ch * 8];
            }
        }
        // h' frag: 2 nb * 7 s * 64 slots = 896
        #pragma unroll
        for (int j = 0; j < 2; ++j) {
            int it = tid + j * 512;
            if (it < 896) {
                int slot = it & 63;
                int q = it >> 6;          // 0..13
                int s = q % 7, nb = q / 7;
                *(v8bf*)(HF + (size_t)((nb0 + nb) * KSTEPS + s) * 512 + slot * 8) =
                    *(const v8bf*)&T[nb * 16 + (slot & 15)][s * 32 + (slot >> 4) * 8];
            }
        }
    } else {
        // fp32 output rows
        #pragma unroll
        for (int j = 0; j < 2; ++j) {
            int it = tid + j * 512;
            if (it < 800) {
                int row = it / 25, ch = it - row * 25;
                int gr = bm + row;
                if (gr < M) {
                    v8bf o = *(const v8bf*)&T[row][ch * 8];
                    float4* q0 = (float4*)(DoutF + (size_t)gr * DIMN + ch * 8);
                    q0[0] = make_float4((float)o[0], (float)o[1], (float)o[2], (float)o[3]);
                    q0[1] = make_float4((float)o[4], (float)o[5], (float)o[6], (float)o[7]);
                }
            }
        }
    }
}

extern "C" void kernel_launch(void* const* d_in, const int* in_sizes, int n_in,
                              void* d_out, int out_size, void* d_ws, size_t ws_size,
                              hipStream_t stream)
{
    const int*   edges = (const int*)  d_in[0];
    const float* ent   = (const float*)d_in[1];
    const float* relE  = (const float*)d_in[2];
    const float* Wm1   = (const float*)d_in[3];
    const float* Wl1   = (const float*)d_in[4];
    const float* Wm2   = (const float*)d_in[5];
    const float* Wl2   = (const float*)d_in[6];
    const float* Wtg   = (const float*)d_in[7];
    const float* bias  = (const float*)d_in[8];
    float* Dout = (float*)d_out;

    const size_t NM    = (size_t)NNODES * DIMN;
    const size_t FRAGN = (size_t)NBN * FRAG_STRIDE;

    __bf16* hR   = (__bf16*)d_ws;                      // h row-major (gather + mega-epilogue)
    __bf16* hF   = hR + NM;                            // h fragment (GEMM-A)
    __bf16* SF   = hF + FRAGN;                         // S1/S2 fragment
    __bf16* BR   = SF + FRAGN;                         // layer-1 out rows (gather)
    __bf16* BF   = BR + NM;                            // layer-1 out fragment
    __bf16* RnR  = BF + FRAGN;                         // normalized relations rows
    __bf16* Wpk  = RnR + (size_t)NREL * DIMN;          // 5 packed weights
    __bf16* pWm1 = Wpk + 0 * (size_t)WPK_ELEMS;
    __bf16* pWl1 = Wpk + 1 * (size_t)WPK_ELEMS;
    __bf16* pWm2 = Wpk + 2 * (size_t)WPK_ELEMS;
    __bf16* pWl2 = Wpk + 3 * (size_t)WPK_ELEMS;
    __bf16* pWtg = Wpk + 4 * (size_t)WPK_ELEMS;
    int*  counts = (int*)(Wpk + 5 * (size_t)WPK_ELEMS);
    int2* sorted = (int2*)(counts + NNODES);
    int*  offs   = (int*)(sorted + NEDGES);
    int*  bsum   = offs + (NNODES + 1);
    int*  stmp   = bsum + 256;

    dim3 blk(256);
    const int GD = (NNODES + 63) / 64;      // 1563 (dual, BM=64, 512 thr)
    const int GM = (NNODES + 31) / 32;      // 3125 (mega, BM=32, 512 thr)
    dim3 ngrid32((NNODES * 32 + 255) / 256);
    dim3 rgrid32((NREL * 32 + 255) / 256);
    dim3 agrid((NNODES + 3) / 4);
    dim3 egrid((NEDGES + 255) / 256);
    const int NSB = (NNODES + SCAN_B - 1) / SCAN_B;

    pack_w<<<dim3((5 * KSTEPS * NB16 * 64 + 255) / 256), blk, 0, stream>>>(Wm1, Wl1, Wm2, Wl2, Wtg, Wpk);
    l2norm_pro<<<ngrid32, blk, 0, stream>>>(ent, hR, hF, NNODES);
    l2norm_pro<<<rgrid32, blk, 0, stream>>>(relE, RnR, nullptr, NREL);

    for (int t = 0; t < 3; ++t) {
        const int* ed = edges + (size_t)t * NEDGES * 3;
        // ---- CSR build ----
        hipMemsetAsync(counts, 0, NNODES * sizeof(int), stream);
        edge_hist<<<egrid, blk, 0, stream>>>(ed, counts, NEDGES);
        scan1<<<NSB, SCAN_B, 0, stream>>>(counts, stmp, bsum, NNODES);
        scan2<<<1, 128, 0, stream>>>(bsum, NSB);
        scan3<<<NSB, SCAN_B, 0, stream>>>(stmp, bsum, offs, NNODES);
        hipMemsetAsync(counts, 0, NNODES * sizeof(int), stream);   // cursor
        edge_fill<<<egrid, blk, 0, stream>>>(ed, offs, counts, sorted, NEDGES);
        // ---- layer 1 (linearity: aggregate in h-space, then fused dual-stream GEMM) ----
        agg_S<<<agrid, blk, 0, stream>>>(offs, sorted, hR, RnR, SF, NNODES);
        gemm_dual<<<GD, dim3(512), 0, stream>>>(SF, pWm1, hF, pWl1, BR, BF, NNODES);
        // ---- layer 2 + gate + blend + norms (mega) ----
        agg_S<<<agrid, blk, 0, stream>>>(offs, sorted, BR, RnR, SF, NNODES);
        gemm_mega<<<GM, dim3(512), 0, stream>>>(SF, pWm2, BF, pWl2, hF, pWtg, bias,
                                                hR, hF, Dout, NNODES, (t == 2) ? 1 : 0);
    }
}

// Round 6
// 967.318 us; speedup vs baseline: 1.7962x; 1.0283x over previous
//
#include <hip/hip_runtime.h>
#include <math.h>

#define DIMN   200
#define NNODES 100000
#define NREL   500
#define NEDGES 200000
#define TSTEPS 3
#define KSTEPS 7            // K padded 200 -> 224 = 7*32
#define NB16   16           // N padded 200 -> 256
#define WPK_ELEMS (KSTEPS * NB16 * 64 * 8)   // 57344 bf16 per weight
#define SCAN_B 1024
#define NBN    6252         // node fragment blocks (16 rows each)
#define FRAG_STRIDE 3584    // elems per frag block = KSTEPS*512

typedef float  v4f  __attribute__((ext_vector_type(4)));
typedef __bf16 v8bf __attribute__((ext_vector_type(8)));

// A-fragment layout: element (row r in block nb, k = c*8+j) at
//   (nb*KSTEPS + c/4)*512 + (c%4)*128 + r*8 + j        (c = chunk 0..27)
__device__ __forceinline__ size_t frag_chunk(int nb, int c, int r) {
    return (size_t)(nb * KSTEPS + (c >> 2)) * 512 + (size_t)((c & 3) * 128 + r * 8);
}

// ---------------- prologue l2norm: fp32 rows -> bf16 row + optional bf16 frag ----------------
__launch_bounds__(256)
__global__ void l2norm_pro(const float* __restrict__ in, __bf16* __restrict__ outR,
                           __bf16* __restrict__ outF, int nrows)
{
    int idx  = blockIdx.x * 256 + threadIdx.x;
    int node = idx >> 5;
    int ch   = idx & 31;
    if (node >= nrows) return;
    float v[8] = {};
    if (ch < 25) {
        const float4* p = (const float4*)(in + (size_t)node * DIMN + ch * 8);
        float4 f0 = p[0], f1 = p[1];
        v[0]=f0.x; v[1]=f0.y; v[2]=f0.z; v[3]=f0.w;
        v[4]=f1.x; v[5]=f1.y; v[6]=f1.z; v[7]=f1.w;
    }
    float ss = 0.0f;
    #pragma unroll
    for (int k = 0; k < 8; ++k) ss += v[k] * v[k];
    #pragma unroll
    for (int off = 16; off; off >>= 1) ss += __shfl_xor(ss, off, 64);
    float s = 1.0f / fmaxf(sqrtf(ss), 1e-12f);
    #pragma unroll
    for (int k = 0; k < 8; ++k) v[k] *= s;
    if (ch < 25) {
        v8bf o;
        #pragma unroll
        for (int k = 0; k < 8; ++k) o[k] = (__bf16)v[k];
        *(v8bf*)(outR + (size_t)node * DIMN + ch * 8) = o;
    }
    if (outF && ch < 28) {
        v8bf o;
        #pragma unroll
        for (int k = 0; k < 8; ++k) o[k] = (ch < 25) ? (__bf16)v[k] : (__bf16)0.0f;
        *(v8bf*)(outF + frag_chunk(node >> 4, ch, node & 15)) = o;
    }
}

// ---------------- batched CSR build over (t,node) super-nodes ----------------
// R6: all 3 timesteps' CSRs built once upfront (edges don't depend on h).
// 21 dispatches -> 6; removes the chain from between compute kernels.
__launch_bounds__(256)
__global__ void edge_hist3(const int* __restrict__ edges, int* __restrict__ counts)
{
    int e = blockIdx.x * 256 + threadIdx.x;
    if (e < TSTEPS * NEDGES) {
        int t = e / NEDGES;
        atomicAdd(&counts[t * NNODES + edges[(size_t)e * 3 + 2]], 1);
    }
}

__launch_bounds__(SCAN_B)
__global__ void scan1(const int* __restrict__ counts, int* __restrict__ tmp,
                      int* __restrict__ bsum, int n)
{
    __shared__ int sh[SCAN_B];
    int i = blockIdx.x * SCAN_B + threadIdx.x;
    int v = (i < n) ? counts[i] : 0;
    sh[threadIdx.x] = v;
    __syncthreads();
    for (int off = 1; off < SCAN_B; off <<= 1) {
        int t = (threadIdx.x >= off) ? sh[threadIdx.x - off] : 0;
        __syncthreads();
        sh[threadIdx.x] += t;
        __syncthreads();
    }
    if (i < n) tmp[i] = sh[threadIdx.x];
    if (threadIdx.x == SCAN_B - 1) bsum[blockIdx.x] = sh[threadIdx.x];
}

// block-sum scan widened to 1024 (NSB for 300k nodes = 293 blocks)
__launch_bounds__(SCAN_B)
__global__ void scan2(int* __restrict__ bsum, int nb)
{
    __shared__ int sh[SCAN_B];
    int v = (threadIdx.x < nb) ? bsum[threadIdx.x] : 0;
    sh[threadIdx.x] = v;
    __syncthreads();
    for (int off = 1; off < SCAN_B; off <<= 1) {
        int t = (threadIdx.x >= off) ? sh[threadIdx.x - off] : 0;
        __syncthreads();
        sh[threadIdx.x] += t;
        __syncthreads();
    }
    if (threadIdx.x < nb) bsum[threadIdx.x] = sh[threadIdx.x] - v;
}

__launch_bounds__(SCAN_B)
__global__ void scan3(const int* __restrict__ tmp, const int* __restrict__ bsum,
                      int* __restrict__ offs, int n)
{
    int i = blockIdx.x * SCAN_B + threadIdx.x;
    if (i < n) offs[i + 1] = tmp[i] + bsum[blockIdx.x];
    if (i == 0) offs[0] = 0;
}

__launch_bounds__(256)
__global__ void edge_fill3(const int* __restrict__ edges, const int* __restrict__ offs,
                           int* __restrict__ cursor, int2* __restrict__ sorted)
{
    int e = blockIdx.x * 256 + threadIdx.x;
    if (e >= TSTEPS * NEDGES) return;
    int t = e / NEDGES;
    int s = edges[(size_t)e * 3 + 0];
    int r = edges[(size_t)e * 3 + 1];
    int d = edges[(size_t)e * 3 + 2];
    int sn = t * NNODES + d;
    int p = offs[sn] + atomicAdd(&cursor[sn], 1);
    sorted[p] = make_int2(s, r);
}

// ---------------- aggregate in h-space: S = segsum(x[src] + r[rel]) / max(deg,1) ----------------
// offs is a per-t base pointer into the continuous 3N+1 cumsum; sorted positions are global.
__launch_bounds__(256)
__global__ void agg_S(const int* __restrict__ offs, const int2* __restrict__ sorted,
                      const __bf16* __restrict__ XR, const __bf16* __restrict__ RnR,
                      __bf16* __restrict__ SF, int nnodes)
{
    int wave = (int)((blockIdx.x * blockDim.x + threadIdx.x) >> 6);
    int lane = threadIdx.x & 63;
    if (wave >= nnodes) return;
    int beg = offs[wave], end = offs[wave + 1];
    int ch = lane & 31;
    bool act = ch < 25;

    float acc[8] = {};
    for (int e = beg; e < end; ++e) {
        int2 sr = sorted[e];
        const __bf16* base = (lane < 32) ? (XR + (size_t)sr.x * DIMN)
                                         : (RnR + (size_t)sr.y * DIMN);
        v8bf v = {};
        if (act) v = *(const v8bf*)(base + ch * 8);
        #pragma unroll
        for (int k = 0; k < 8; ++k) acc[k] += (float)v[k];
    }
    #pragma unroll
    for (int k = 0; k < 8; ++k) acc[k] += __shfl_xor(acc[k], 32, 64);

    float rdeg = 1.0f / fmaxf((float)(end - beg), 1.0f);
    if (lane < 32 && ch < 28) {
        v8bf o;
        #pragma unroll
        for (int k = 0; k < 8; ++k) o[k] = act ? (__bf16)(acc[k] * rdeg) : (__bf16)0.0f;
        *(v8bf*)(SF + frag_chunk(wave >> 4, ch, wave & 15)) = o;
    }
}

// ---------------- weight pack: fp32 W[200x200] -> bf16 MFMA-B-fragment-linear ----------------
__launch_bounds__(256)
__global__ void pack_w(const float* __restrict__ W0, const float* __restrict__ W1,
                       const float* __restrict__ W2, const float* __restrict__ W3,
                       const float* __restrict__ W4, __bf16* __restrict__ out)
{
    int id = blockIdx.x * 256 + threadIdx.x;
    const int nchunk = KSTEPS * NB16 * 64;        // 7168
    if (id >= 5 * nchunk) return;
    int wi = id / nchunk;
    int c  = id % nchunk;
    const float* W = wi == 0 ? W0 : wi == 1 ? W1 : wi == 2 ? W2 : wi == 3 ? W3 : W4;
    int s    = c >> 10;
    int nb   = (c & 1023) >> 6;
    int lane = c & 63;
    int kbase = s * 32 + (lane >> 4) * 8;
    int n     = nb * 16 + (lane & 15);
    __bf16* dst = out + (size_t)wi * WPK_ELEMS + (size_t)c * 8;
    #pragma unroll
    for (int j = 0; j < 8; ++j) {
        int k = kbase + j;
        float v = (k < DIMN && n < DIMN) ? W[k * DIMN + n] : 0.0f;
        dst[j] = (__bf16)v;
    }
}

// ---------------- G1: Out = A1@W1 + A2@W2 ; BM=64, 8 waves x ni=2 (R5 proven) ----------------
__launch_bounds__(512)
__global__ void gemm_dual(const __bf16* __restrict__ A1, const __bf16* __restrict__ W1,
                          const __bf16* __restrict__ A2, const __bf16* __restrict__ W2,
                          __bf16* __restrict__ OutR, __bf16* __restrict__ OutF, int M)
{
    const int tid  = threadIdx.x;
    const int w    = tid >> 6;          // 0..7
    const int lane = tid & 63;
    const int rlo  = lane & 15;
    const int g    = lane >> 4;
    const int nb0  = blockIdx.x * 4;
    const int bm   = blockIdx.x * 64;

    __shared__ __bf16 T[64][264];

    v4f acc[4][2];
    #pragma unroll
    for (int mi = 0; mi < 4; ++mi)
        #pragma unroll
        for (int ni = 0; ni < 2; ++ni)
            acc[mi][ni] = (v4f){0.f, 0.f, 0.f, 0.f};

    // wave w covers col blocks w*2 + ni (cols w*32 + ni*16 + rlo)
    const __bf16* w1b = W1 + (size_t)(w * 2 * 64 + lane) * 8;
    const __bf16* w2b = W2 + (size_t)(w * 2 * 64 + lane) * 8;

    #pragma unroll
    for (int s = 0; s < KSTEPS; ++s) {
        v8bf b1[2], b2[2];
        #pragma unroll
        for (int ni = 0; ni < 2; ++ni) {
            size_t bo = ((size_t)s * NB16 * 64 + ni * 64) * 8;
            b1[ni] = *(const v8bf*)(w1b + bo);
            b2[ni] = *(const v8bf*)(w2b + bo);
        }
        #pragma unroll
        for (int mi = 0; mi < 4; ++mi) {
            size_t aoff = (size_t)((nb0 + mi) * KSTEPS + s) * 512 + lane * 8;
            v8bf a1 = *(const v8bf*)(A1 + aoff);
            v8bf a2 = *(const v8bf*)(A2 + aoff);
            #pragma unroll
            for (int ni = 0; ni < 2; ++ni)
                acc[mi][ni] = __builtin_amdgcn_mfma_f32_16x16x32_bf16(a1, b1[ni], acc[mi][ni], 0, 0, 0);
            #pragma unroll
            for (int ni = 0; ni < 2; ++ni)
                acc[mi][ni] = __builtin_amdgcn_mfma_f32_16x16x32_bf16(a2, b2[ni], acc[mi][ni], 0, 0, 0);
        }
    }

    // D -> LDS tile (row = mi*16 + g*4 + reg, col = w*32 + ni*16 + rlo)
    #pragma unroll
    for (int mi = 0; mi < 4; ++mi)
        #pragma unroll
        for (int reg = 0; reg < 4; ++reg)
            #pragma unroll
            for (int ni = 0; ni < 2; ++ni)
                T[mi * 16 + g * 4 + reg][w * 32 + ni * 16 + rlo] = (__bf16)acc[mi][ni][reg];
    __syncthreads();

    // frag emit: 4 nb * 7 s * 64 slots = 1792
    #pragma unroll
    for (int j = 0; j < 4; ++j) {
        int it = tid + j * 512;
        if (it < 1792) {
            int slot = it & 63;
            int q = it >> 6;          // 0..27
            int s = q % 7, nb = q / 7;
            *(v8bf*)(OutF + (size_t)((nb0 + nb) * KSTEPS + s) * 512 + slot * 8) =
                *(const v8bf*)&T[nb * 16 + (slot & 15)][s * 32 + (slot >> 4) * 8];
        }
    }
    // row emit: 64 rows * 25 chunks = 1600
    #pragma unroll
    for (int j = 0; j < 4; ++j) {
        int it = tid + j * 512;
        if (it < 1600) {
            int row = it / 25, ch = it - row * 25;
            int gr = bm + row;
            if (gr < M)
                *(v8bf*)(OutR + (size_t)gr * DIMN + ch * 8) = *(const v8bf*)&T[row][ch * 8];
        }
    }
}

// ---------------- G2 mega (R4 exact form: global A, 8 waves x ni=2, BM=32) ----------------
// R5 lesson: LDS-staged A dropped occupancy 75->41% (45KB LDS) and was net -10us.
// R4 form: VGPR 32, LDS 18944, occ ~75%, 124us.
__launch_bounds__(512)
__global__ void gemm_mega(const __bf16* __restrict__ A1, const __bf16* __restrict__ W1,
                          const __bf16* __restrict__ A2, const __bf16* __restrict__ W2,
                          const __bf16* __restrict__ A3, const __bf16* __restrict__ W3,
                          const float* __restrict__ Bias,
                          __bf16* __restrict__ HR, __bf16* __restrict__ HF,
                          float* __restrict__ DoutF, int M, int finalStep)
{
    const int tid  = threadIdx.x;
    const int w    = tid >> 6;          // 0..7
    const int lane = tid & 63;
    const int rlo  = lane & 15;
    const int g    = lane >> 4;
    const int nb0  = blockIdx.x * 2;
    const int bm   = blockIdx.x * 32;

    __shared__ __bf16 T[32][264];
    __shared__ float  rsq1[32][8];
    __shared__ float  rsq2[32][8];

    v4f acc1[2][2], acc2[2][2];
    #pragma unroll
    for (int mi = 0; mi < 2; ++mi)
        #pragma unroll
        for (int ni = 0; ni < 2; ++ni) {
            acc1[mi][ni] = (v4f){0.f, 0.f, 0.f, 0.f};
            acc2[mi][ni] = (v4f){0.f, 0.f, 0.f, 0.f};
        }

    // wave w covers col blocks nb = w*2 + ni  (cols w*32 + ni*16 + rlo)
    const __bf16* w1b = W1 + (size_t)(w * 2 * 64 + lane) * 8;
    const __bf16* w2b = W2 + (size_t)(w * 2 * 64 + lane) * 8;
    const __bf16* w3b = W3 + (size_t)(w * 2 * 64 + lane) * 8;

    for (int s = 0; s < KSTEPS; ++s) {
        v8bf b1[2], b2[2], b3[2];
        #pragma unroll
        for (int ni = 0; ni < 2; ++ni) {
            size_t bo = ((size_t)s * NB16 * 64 + ni * 64) * 8;
            b1[ni] = *(const v8bf*)(w1b + bo);
            b2[ni] = *(const v8bf*)(w2b + bo);
            b3[ni] = *(const v8bf*)(w3b + bo);
        }
        #pragma unroll
        for (int mi = 0; mi < 2; ++mi) {
            size_t aoff = (size_t)((nb0 + mi) * KSTEPS + s) * 512 + lane * 8;
            v8bf a1 = *(const v8bf*)(A1 + aoff);
            v8bf a2 = *(const v8bf*)(A2 + aoff);
            v8bf a3 = *(const v8bf*)(A3 + aoff);
            #pragma unroll
            for (int ni = 0; ni < 2; ++ni)
                acc1[mi][ni] = __builtin_amdgcn_mfma_f32_16x16x32_bf16(a1, b1[ni], acc1[mi][ni], 0, 0, 0);
            #pragma unroll
            for (int ni = 0; ni < 2; ++ni)
                acc1[mi][ni] = __builtin_amdgcn_mfma_f32_16x16x32_bf16(a2, b2[ni], acc1[mi][ni], 0, 0, 0);
            #pragma unroll
            for (int ni = 0; ni < 2; ++ni)
                acc2[mi][ni] = __builtin_amdgcn_mfma_f32_16x16x32_bf16(a3, b3[ni], acc2[mi][ni], 0, 0, 0);
        }
    }

    // cur row sums-of-squares (cols >= 200 are zero via weight padding)
    #pragma unroll
    for (int mi = 0; mi < 2; ++mi)
        #pragma unroll
        for (int reg = 0; reg < 4; ++reg) {
            float ss = 0.0f;
            #pragma unroll
            for (int ni = 0; ni < 2; ++ni) ss += acc1[mi][ni][reg] * acc1[mi][ni][reg];
            ss += __shfl_xor(ss, 1, 64);
            ss += __shfl_xor(ss, 2, 64);
            ss += __shfl_xor(ss, 4, 64);
            ss += __shfl_xor(ss, 8, 64);
            if (rlo == 0) rsq1[mi * 16 + g * 4 + reg][w] = ss;
        }
    // stage h rows into T (buffer reused; overwritten only after blend completes)
    #pragma unroll
    for (int j = 0; j < 2; ++j) {
        int it = tid + j * 512;
        if (it < 800) {
            int row = it / 25, ch = it - row * 25;
            int gr = bm + row;
            v8bf hv = {};
            if (gr < M) hv = *(const v8bf*)(HR + (size_t)gr * DIMN + ch * 8);
            *(v8bf*)&T[row][ch * 8] = hv;
        }
    }
    __syncthreads();

    // blend: v = gate*cur + (1-gate)*h  (store into acc1), second row reduce
    #pragma unroll
    for (int mi = 0; mi < 2; ++mi)
        #pragma unroll
        for (int reg = 0; reg < 4; ++reg) {
            int rl = mi * 16 + g * 4 + reg;
            float tot = rsq1[rl][0] + rsq1[rl][1] + rsq1[rl][2] + rsq1[rl][3]
                      + rsq1[rl][4] + rsq1[rl][5] + rsq1[rl][6] + rsq1[rl][7];
            float sc1 = 1.0f / fmaxf(sqrtf(tot), 1e-12f);
            float ss = 0.0f;
            #pragma unroll
            for (int ni = 0; ni < 2; ++ni) {
                int c = w * 32 + ni * 16 + rlo;
                float v = 0.0f;
                if (c < DIMN) {
                    float cur = acc1[mi][ni][reg] * sc1;
                    float gg  = 1.0f / (1.0f + __expf(-(acc2[mi][ni][reg] + Bias[c])));
                    float hh  = (float)T[rl][c];
                    v = gg * cur + (1.0f - gg) * hh;
                }
                acc1[mi][ni][reg] = v;
                ss += v * v;
            }
            ss += __shfl_xor(ss, 1, 64);
            ss += __shfl_xor(ss, 2, 64);
            ss += __shfl_xor(ss, 4, 64);
            ss += __shfl_xor(ss, 8, 64);
            if (rlo == 0) rsq2[rl][w] = ss;
        }
    __syncthreads();

    // final scale -> T (overwrites staged h; all h reads completed before the barrier above)
    #pragma unroll
    for (int mi = 0; mi < 2; ++mi)
        #pragma unroll
        for (int reg = 0; reg < 4; ++reg) {
            int rl = mi * 16 + g * 4 + reg;
            float tot = rsq2[rl][0] + rsq2[rl][1] + rsq2[rl][2] + rsq2[rl][3]
                      + rsq2[rl][4] + rsq2[rl][5] + rsq2[rl][6] + rsq2[rl][7];
            float sc2 = 1.0f / fmaxf(sqrtf(tot), 1e-12f);
            #pragma unroll
            for (int ni = 0; ni < 2; ++ni) {
                int c = w * 32 + ni * 16 + rlo;
                T[rl][c] = (__bf16)(acc1[mi][ni][reg] * sc2);
            }
        }
    __syncthreads();

    if (!finalStep) {
        // h' rows: 32 rows * 25 chunks = 800
        #pragma unroll
        for (int j = 0; j < 2; ++j) {
            int it = tid + j * 512;
            if (it < 800) {
                int row = it / 25, ch = it - row * 25;
                int gr = bm + row;
                if (gr < M)
                    *(v8bf*)(HR + (size_t)gr * DIMN + ch * 8) = *(const v8bf*)&T[row][ch * 8];
            }
        }
        // h' frag: 2 nb * 7 s * 64 slots = 896
        #pragma unroll
        for (int j = 0; j < 2; ++j) {
            int it = tid + j * 512;
            if (it < 896) {
                int slot = it & 63;
                int q = it >> 6;          // 0..13
                int s = q % 7, nb = q / 7;
                *(v8bf*)(HF + (size_t)((nb0 + nb) * KSTEPS + s) * 512 + slot * 8) =
                    *(const v8bf*)&T[nb * 16 + (slot & 15)][s * 32 + (slot >> 4) * 8];
            }
        }
    } else {
        // fp32 output rows
        #pragma unroll
        for (int j = 0; j < 2; ++j) {
            int it = tid + j * 512;
            if (it < 800) {
                int row = it / 25, ch = it - row * 25;
                int gr = bm + row;
                if (gr < M) {
                    v8bf o = *(const v8bf*)&T[row][ch * 8];
                    float4* q0 = (float4*)(DoutF + (size_t)gr * DIMN + ch * 8);
                    q0[0] = make_float4((float)o[0], (float)o[1], (float)o[2], (float)o[3]);
                    q0[1] = make_float4((float)o[4], (float)o[5], (float)o[6], (float)o[7]);
                }
            }
        }
    }
}

extern "C" void kernel_launch(void* const* d_in, const int* in_sizes, int n_in,
                              void* d_out, int out_size, void* d_ws, size_t ws_size,
                              hipStream_t stream)
{
    const int*   edges = (const int*)  d_in[0];
    const float* ent   = (const float*)d_in[1];
    const float* relE  = (const float*)d_in[2];
    const float* Wm1   = (const float*)d_in[3];
    const float* Wl1   = (const float*)d_in[4];
    const float* Wm2   = (const float*)d_in[5];
    const float* Wl2   = (const float*)d_in[6];
    const float* Wtg   = (const float*)d_in[7];
    const float* bias  = (const float*)d_in[8];
    float* Dout = (float*)d_out;

    const size_t NM    = (size_t)NNODES * DIMN;
    const size_t FRAGN = (size_t)NBN * FRAG_STRIDE;

    __bf16* hR   = (__bf16*)d_ws;                      // h row-major (gather + mega-epilogue)
    __bf16* hF   = hR + NM;                            // h fragment (GEMM-A)
    __bf16* SF   = hF + FRAGN;                         // S1/S2 fragment
    __bf16* BR   = SF + FRAGN;                         // layer-1 out rows (gather)
    __bf16* BF   = BR + NM;                            // layer-1 out fragment
    __bf16* RnR  = BF + FRAGN;                         // normalized relations rows
    __bf16* Wpk  = RnR + (size_t)NREL * DIMN;          // 5 packed weights
    __bf16* pWm1 = Wpk + 0 * (size_t)WPK_ELEMS;
    __bf16* pWl1 = Wpk + 1 * (size_t)WPK_ELEMS;
    __bf16* pWm2 = Wpk + 2 * (size_t)WPK_ELEMS;
    __bf16* pWl2 = Wpk + 3 * (size_t)WPK_ELEMS;
    __bf16* pWtg = Wpk + 4 * (size_t)WPK_ELEMS;
    // batched CSR arrays over 3N super-nodes
    int*  counts = (int*)(Wpk + 5 * (size_t)WPK_ELEMS);
    int*  cursor = counts + TSTEPS * NNODES;
    int2* sorted = (int2*)(cursor + TSTEPS * NNODES);
    int*  offs   = (int*)(sorted + TSTEPS * NEDGES);
    int*  bsum   = offs + (TSTEPS * NNODES + 1);
    int*  stmp   = bsum + SCAN_B;

    dim3 blk(256);
    const int GD = (NNODES + 63) / 64;      // 1563 (dual, BM=64, 512 thr)
    const int GM = (NNODES + 31) / 32;      // 3125 (mega, BM=32, 512 thr)
    dim3 ngrid32((NNODES * 32 + 255) / 256);
    dim3 rgrid32((NREL * 32 + 255) / 256);
    dim3 agrid((NNODES + 3) / 4);
    dim3 egrid3((TSTEPS * NEDGES + 255) / 256);
    const int NTOT = TSTEPS * NNODES;               // 300000
    const int NSB  = (NTOT + SCAN_B - 1) / SCAN_B;  // 293

    // ---- weights + prologue norms ----
    pack_w<<<dim3((5 * KSTEPS * NB16 * 64 + 255) / 256), blk, 0, stream>>>(Wm1, Wl1, Wm2, Wl2, Wtg, Wpk);
    l2norm_pro<<<ngrid32, blk, 0, stream>>>(ent, hR, hF, NNODES);
    l2norm_pro<<<rgrid32, blk, 0, stream>>>(relE, RnR, nullptr, NREL);

    // ---- batched CSR build (all timesteps) ----
    hipMemsetAsync(counts, 0, 2 * NTOT * sizeof(int), stream);   // counts + cursor
    edge_hist3<<<egrid3, blk, 0, stream>>>(edges, counts);
    scan1<<<NSB, SCAN_B, 0, stream>>>(counts, stmp, bsum, NTOT);
    scan2<<<1, SCAN_B, 0, stream>>>(bsum, NSB);
    scan3<<<NSB, SCAN_B, 0, stream>>>(stmp, bsum, offs, NTOT);
    edge_fill3<<<egrid3, blk, 0, stream>>>(edges, offs, cursor, sorted);

    for (int t = 0; t < 3; ++t) {
        const int* offsT = offs + (size_t)t * NNODES;
        // ---- layer 1 (linearity: aggregate in h-space, then fused dual-stream GEMM) ----
        agg_S<<<agrid, blk, 0, stream>>>(offsT, sorted, hR, RnR, SF, NNODES);
        gemm_dual<<<GD, dim3(512), 0, stream>>>(SF, pWm1, hF, pWl1, BR, BF, NNODES);
        // ---- layer 2 + gate + blend + norms (mega) ----
        agg_S<<<agrid, blk, 0, stream>>>(offsT, sorted, BR, RnR, SF, NNODES);
        gemm_mega<<<GM, dim3(512), 0, stream>>>(SF, pWm2, BF, pWl2, hF, pWtg, bias,
                                                hR, hF, Dout, NNODES, (t == 2) ? 1 : 0);
    }
}